// Round 5
// baseline (634.937 us; speedup 1.0000x reference)
//
#include <hip/hip_runtime.h>
#include <hip/hip_bf16.h>
#include <cstdint>
#include <cstddef>

using bf16 = __hip_bfloat16;
#define DEV __device__ __forceinline__

typedef short s16x8 __attribute__((ext_vector_type(8)));
typedef float f32x4 __attribute__((ext_vector_type(4)));

DEV float b2f(bf16 x){ return __bfloat162float(x); }
DEV bf16  f2b(float x){ return __float2bfloat16(x); }
DEV float u2f(unsigned u){ union{unsigned u; float f;} c; c.u=u; return c.f; }
DEV unsigned f2u(float f){ union{float f; unsigned u;} c; c.f=f; return c.u; }
DEV unsigned short f2bu(float f){ unsigned u = f2u(f); u += 0x7FFFu + ((u>>16)&1u); return (unsigned short)(u>>16); }
DEV float sigm(float x){ return 1.f/(1.f+__expf(-x)); }

// dtype-adaptive input load / output store (bf==1 -> bf16, else fp32)
DEV float ld(const void* p, long i, int bf){
  return bf ? b2f(((const bf16*)p)[i]) : ((const float*)p)[i];
}
DEV void st(void* p, long i, float v, int bf){
  if (bf) ((bf16*)p)[i] = f2b(v); else ((float*)p)[i] = v;
}

constexpr float IMGX = 100.0f;   // 800/8
constexpr float IMGY = 56.0f;    // 448/8
constexpr float LOG_EPS = -15.942385f;  // ln(2^-23)
constexpr float BIN = 53.0f/1056.0f;    // (PC3-1)/(D*(1+D))
constexpr int NC = 25;                  // key chunks (5600 = 25*224)
constexpr int CK = 224;                 // keys per chunk (= 7*32)

// ---- workspace layout (float units) ----
constexpr size_t OFF_Q    = 0;        // 200*128
constexpr size_t OFF_QPE  = 25600;    // 200*128
constexpr size_t OFF_TMP  = 51200;    // 200*384
constexpr size_t OFF_KPE  = 128000;   // 5600*128 (fp32)
constexpr size_t OFF_PM   = 844800;   // 200*25*8
constexpr size_t OFF_PS   = 884800;   // 200*25*8
constexpr size_t OFF_PO   = 924800;   // 200*25*8*16
constexpr size_t OFF_FPOS = 1564800;  // 5600*2
constexpr size_t OFF_CTR  = 1576000;  // 200*2
constexpr size_t OFF_SIG  = 1576400;  // 200
constexpr size_t OFF_FLAG = 1576600;  // 1 int
constexpr size_t F_TOTAL  = 1576608;
// bf16 region after floats:
constexpr size_t B_KEYS = 0;          // 33600*128
constexpr size_t B_KH   = 4300800;    // 6*8*5600*16
constexpr size_t B_VH   = 8601600;

DEV void unpack2(unsigned u, float* f){ f[0]=u2f(u<<16); f[1]=u2f(u&0xffff0000u); }

// butterfly online-softmax merge across W lanes
template<int W>
DEV void mergeW(float& m, float& s, float (&o)[16]){
  #pragma unroll
  for (int off=W/2; off>=1; off>>=1){
    float m2 = __shfl_xor(m, off);
    float s2 = __shfl_xor(s, off);
    float mn = fmaxf(m, m2);
    float ea = (m  > -3.0e38f) ? __expf(m  - mn) : 0.f;
    float eb = (m2 > -3.0e38f) ? __expf(m2 - mn) : 0.f;
    s = s*ea + s2*eb;
    #pragma unroll
    for (int d=0; d<16; ++d){
      float od = __shfl_xor(o[d], off);
      o[d] = o[d]*ea + od*eb;
    }
    m = mn;
  }
}

// ================= dtype probe =================
__global__ void k_probe(const void* ln1g, int* flag){
  unsigned u = *(const unsigned*)ln1g;
  *flag = ((u & 0xFFFFu) == 0x3F80u) ? 1 : 0;
}

// ================= prep kernels =================
__global__ void k_transpose(const void* __restrict__ iff, bf16* __restrict__ keys,
                            const int* __restrict__ flg){
  __shared__ float t[32][33];
  int bf = *flg;
  int k0 = blockIdx.x*32, c0 = blockIdx.y*32, v = blockIdx.z;
  int tx = threadIdx.x, ty = threadIdx.y;
  #pragma unroll
  for (int i=0;i<4;++i){
    int c = c0 + ty + i*8;
    t[ty+i*8][tx] = ld(iff, (long)(v*128 + c)*5600 + k0 + tx, bf);
  }
  __syncthreads();
  #pragma unroll
  for (int i=0;i<4;++i){
    int k = k0 + ty + i*8;
    keys[(size_t)(v*5600 + k)*128 + c0 + tx] = f2b(t[tx][ty+i*8]);
  }
}

__global__ void k_feat_pos(const void* __restrict__ nifp, float* __restrict__ fpos,
                           const int* __restrict__ flg){
  int bf = *flg;
  int k = blockIdx.x*blockDim.x + threadIdx.x;
  if (k >= 5600) return;
  fpos[2*k]   = sigm(ld(nifp,2*k,bf))*IMGX - 0.5f;
  fpos[2*k+1] = sigm(ld(nifp,2*k+1,bf))*IMGY - 0.5f;
}

// centers + out1 copy + per-query inverse + pos3d
__global__ __launch_bounds__(64) void k_prep(
    const void* __restrict__ niqp, const void* __restrict__ l2i,
    const int* __restrict__ view, float* __restrict__ ctr,
    void* __restrict__ out, const int* __restrict__ flg){
  __shared__ float M[16];
  __shared__ float cs[2];
  int bf = *flg;
  int n = blockIdx.x, t = threadIdx.x;
  if (t == 0){
    float p0 = ld(niqp,2*n,bf), p1 = ld(niqp,2*n+1,bf);
    float cx = sigm(p0)*IMGX, cy = sigm(p1)*IMGY;
    ctr[2*n] = cx; ctr[2*n+1] = cy;
    cs[0] = cx; cs[1] = cy;
    st(out, 25600 + 2*n,   p0, bf);
    st(out, 25600 + 2*n+1, p1, bf);
    int v = view[n];
    float a[4][8];
    for (int i=0;i<4;++i)
      for (int j=0;j<4;++j){ a[i][j] = ld(l2i, v*16+i*4+j, bf); a[i][4+j] = (i==j)?1.f:0.f; }
    for (int col=0; col<4; ++col){
      int p = col; float best = fabsf(a[col][col]);
      for (int r=col+1;r<4;++r){ float tt=fabsf(a[r][col]); if (tt>best){best=tt;p=r;} }
      if (p!=col) for (int j=0;j<8;++j){ float tt=a[col][j]; a[col][j]=a[p][j]; a[p][j]=tt; }
      float inv = 1.f/a[col][col];
      for (int j=0;j<8;++j) a[col][j]*=inv;
      for (int r=0;r<4;++r){
        if (r==col) continue;
        float f = a[r][col];
        for (int j=0;j<8;++j) a[r][j] -= f*a[col][j];
      }
    }
    for (int i=0;i<4;++i) for (int j=0;j<4;++j) M[i*4+j] = a[i][4+j];
  }
  __syncthreads();
  if (t < 32){
    int d = t;
    float px = cs[0]*8.f, py = cs[1]*8.f;
    float dep = 1.f + BIN * (float)d * (float)(d+1);
    float x = px*dep, y = py*dep;
    #pragma unroll
    for (int i=0;i<3;++i){
      float val = M[i*4]*x + M[i*4+1]*y + M[i*4+2]*dep + M[i*4+3];
      st(out, 26000 + n*96 + d*3 + i, val, bf);
    }
  }
}

// ================= generic small linear (Y fp32) =================
template<int ACT>
__global__ void k_linear(const float* __restrict__ X, const float* __restrict__ X2,
                         const void* __restrict__ W, long wOff, int ldw,
                         const void* __restrict__ bias, long bOff,
                         float* __restrict__ Y, int K, int N,
                         const int* __restrict__ flg){
  __shared__ float xs[256];
  int bf = *flg;
  int m = blockIdx.x;
  for (int k = threadIdx.x; k < K; k += blockDim.x){
    float v = X[(size_t)m*K + k];
    if (X2) v += X2[(size_t)m*K + k];
    xs[k] = v;
  }
  __syncthreads();
  for (int c = threadIdx.x; c < N; c += blockDim.x){
    float acc = ld(bias, bOff + c, bf);
    for (int k = 0; k < K; ++k) acc = fmaf(xs[k], ld(W, wOff + (long)k*ldw + c, bf), acc);
    if (ACT) acc = fmaxf(acc, 0.f);
    Y[(size_t)m*N + c] = acc;
  }
}

// fused 2-layer pos-embed MLP (small M): y = relu(pos@w1+b1)@w2 + b2
__global__ __launch_bounds__(128) void k_posembed_f(
    const void* __restrict__ pos, const void* __restrict__ w1, long w1Off,
    const void* __restrict__ b1, long b1Off,
    const void* __restrict__ w2, long w2Off,
    const void* __restrict__ b2, long b2Off,
    float* __restrict__ Y, const int* __restrict__ flg){
  __shared__ float hs[128];
  int bf = *flg;
  int m = blockIdx.x, c = threadIdx.x;
  float p0 = ld(pos,2*m,bf), p1 = ld(pos,2*m+1,bf);
  float a = fmaf(p0, ld(w1,w1Off+c,bf), fmaf(p1, ld(w1,w1Off+128+c,bf), ld(b1,b1Off+c,bf)));
  hs[c] = fmaxf(a, 0.f);
  __syncthreads();
  float acc = ld(b2, b2Off+c, bf);
  for (int k = 0; k < 128; ++k) acc = fmaf(hs[k], ld(w2, w2Off + (long)k*128 + c, bf), acc);
  Y[(size_t)m*128 + c] = acc;
}

// ================= kpe via MFMA: kpe = relu(pos@w1+b1)@w2 + b2, M=5600 =================
// grid 88 (64 rows each), block 256; wave w covers cols [32w, 32w+32)
__global__ __launch_bounds__(256) void k_kpe_mfma(
    const void* __restrict__ nifp,
    const void* __restrict__ w1, long w1o, const void* __restrict__ b1, long b1o,
    const void* __restrict__ w2, long w2o, const void* __restrict__ b2, long b2o,
    float* __restrict__ kpe, const int* __restrict__ flg){
  constexpr int XP = 136;
  __shared__ __align__(16) unsigned short xs[64*XP];
  __shared__ float2 pr[64];
  int bf = *flg;
  int r0 = blockIdx.x * 64;
  int tid = threadIdx.x;
  if (tid < 64){
    int k = r0 + tid; if (k > 5599) k = 5599;
    pr[tid] = make_float2(ld(nifp,2*k,bf), ld(nifp,2*k+1,bf));
  }
  __syncthreads();
  for (int idx = tid; idx < 64*64; idx += 256){
    int r = idx >> 6, c2 = (idx & 63)*2;
    float2 p = pr[r];
    #pragma unroll
    for (int u=0;u<2;++u){
      int c = c2+u;
      float a = fmaf(p.x, ld(w1,w1o+c,bf), fmaf(p.y, ld(w1,w1o+128+c,bf), ld(b1,b1o+c,bf)));
      xs[r*XP + c] = f2bu(fmaxf(a, 0.f));
    }
  }
  int wv = tid >> 6;
  int lane = tid & 63;
  int l16 = lane & 15, quad = lane >> 4;
  f32x4 acc[4][2];
  #pragma unroll
  for (int mt=0;mt<4;++mt)
    #pragma unroll
    for (int nt=0;nt<2;++nt) acc[mt][nt] = (f32x4){0.f,0.f,0.f,0.f};
  __syncthreads();
  #pragma unroll
  for (int kc = 0; kc < 4; ++kc){
    s16x8 bfr[2];
    #pragma unroll
    for (int nt = 0; nt < 2; ++nt){
      long base = w2o + (long)(kc*32 + quad*8)*128 + (wv*32 + nt*16 + l16);
      s16x8 bb;
      #pragma unroll
      for (int j = 0; j < 8; ++j) bb[j] = (short)f2bu(ld(w2, base + (long)j*128, bf));
      bfr[nt] = bb;
    }
    s16x8 afr[4];
    #pragma unroll
    for (int mt = 0; mt < 4; ++mt)
      afr[mt] = *(const s16x8*)&xs[(mt*16 + l16)*XP + kc*32 + quad*8];
    #pragma unroll
    for (int mt = 0; mt < 4; ++mt)
      #pragma unroll
      for (int nt = 0; nt < 2; ++nt)
        acc[mt][nt] = __builtin_amdgcn_mfma_f32_16x16x32_bf16(afr[mt], bfr[nt], acc[mt][nt], 0, 0, 0);
  }
  float bv[2];
  #pragma unroll
  for (int nt=0;nt<2;++nt) bv[nt] = ld(b2, b2o + wv*32 + nt*16 + l16, bf);
  #pragma unroll
  for (int mt = 0; mt < 4; ++mt)
    #pragma unroll
    for (int i = 0; i < 4; ++i){
      int gr = r0 + mt*16 + quad*4 + i;
      if (gr < 5600){
        #pragma unroll
        for (int nt = 0; nt < 2; ++nt)
          kpe[(size_t)gr*128 + wv*32 + nt*16 + l16] = acc[mt][nt][i] + bv[nt];
      }
    }
}

// ================= K/V projection — MFMA =================
__global__ __launch_bounds__(256) void k_kv_proj_mfma(
    const bf16* __restrict__ keys, const float* __restrict__ kpe,
    const void* __restrict__ W, long wOff, const void* __restrict__ bias, long bOff,
    bf16* __restrict__ kh, bf16* __restrict__ vh, const int* __restrict__ flg){
  constexpr int XP = 136;
  __shared__ __align__(16) unsigned short xs[64*XP];
  int bf = *flg;
  int r0 = blockIdx.x * 64;
  int tid = threadIdx.x;
  for (int idx = tid; idx < 64*64; idx += 256){
    int r = idx >> 6, c2 = (idx & 63)*2;
    int gr = r0 + r;
    int v = gr / 5600; int k = gr - v*5600;
    float a0 = b2f(keys[(size_t)gr*128 + c2])   + kpe[(size_t)k*128 + c2];
    float a1 = b2f(keys[(size_t)gr*128 + c2+1]) + kpe[(size_t)k*128 + c2+1];
    xs[r*XP + c2]   = f2bu(a0);
    xs[r*XP + c2+1] = f2bu(a1);
  }
  int wv = tid >> 6;
  int lane = tid & 63;
  int l16 = lane & 15, quad = lane >> 4;
  f32x4 acc[4][4];
  #pragma unroll
  for (int mt=0;mt<4;++mt)
    #pragma unroll
    for (int nt=0;nt<4;++nt) acc[mt][nt] = (f32x4){0.f,0.f,0.f,0.f};
  __syncthreads();
  #pragma unroll
  for (int kc = 0; kc < 4; ++kc){
    s16x8 bfr[4];
    #pragma unroll
    for (int nt = 0; nt < 4; ++nt){
      long base = wOff + (long)(kc*32 + quad*8)*384 + (128 + wv*64 + nt*16 + l16);
      s16x8 bb;
      #pragma unroll
      for (int j = 0; j < 8; ++j) bb[j] = (short)f2bu(ld(W, base + (long)j*384, bf));
      bfr[nt] = bb;
    }
    s16x8 afr[4];
    #pragma unroll
    for (int mt = 0; mt < 4; ++mt)
      afr[mt] = *(const s16x8*)&xs[(mt*16 + l16)*XP + kc*32 + quad*8];
    #pragma unroll
    for (int mt = 0; mt < 4; ++mt)
      #pragma unroll
      for (int nt = 0; nt < 4; ++nt)
        acc[mt][nt] = __builtin_amdgcn_mfma_f32_16x16x32_bf16(afr[mt], bfr[nt], acc[mt][nt], 0, 0, 0);
  }
  float bv[4];
  bf16* op[4];
  long ntOff[4];
  #pragma unroll
  for (int nt = 0; nt < 4; ++nt){
    int c = wv*64 + nt*16 + l16;
    bv[nt] = ld(bias, bOff + 128 + c, bf);
    int sel = c >> 7, ch = c & 127;
    int h = ch >> 4, d = ch & 15;
    op[nt] = sel ? vh : kh;
    ntOff[nt] = (long)h*89600 + d;
  }
  #pragma unroll
  for (int mt = 0; mt < 4; ++mt)
    #pragma unroll
    for (int i = 0; i < 4; ++i){
      int gr = r0 + mt*16 + quad*4 + i;
      int v = gr / 5600; int k = gr - v*5600;
      long rowOff = (long)v*716800 + (long)k*16;
      #pragma unroll
      for (int nt = 0; nt < 4; ++nt)
        op[nt][rowOff + ntOff[nt]] = f2b(acc[mt][nt][i] + bv[nt]);
    }
}

// ================= self-attention fused (attn + out-proj + LN) =================
__global__ __launch_bounds__(128) void k_self_attn_f(
    const float* __restrict__ qkv, const int* __restrict__ view,
    const void* __restrict__ W, long wOff, const void* __restrict__ bias, long bOff,
    float* __restrict__ q, const void* __restrict__ g, long gOff,
    const void* __restrict__ b, long bOff2, const int* __restrict__ flg){
  __shared__ float att[128];
  __shared__ float red[128];
  int bf = *flg;
  int n = blockIdx.x, t = threadIdx.x;
  int h = t >> 4, j = t & 15;
  int vn = view[n];
  float qh[16];
  #pragma unroll
  for (int d=0; d<16; ++d) qh[d] = qkv[(size_t)n*384 + h*16 + d] * 0.25f;
  float m = -INFINITY, s = 0.f, o[16];
  #pragma unroll
  for (int d=0; d<16; ++d) o[d]=0.f;
  for (int k = j; k < 200; k += 16){
    float l;
    if (view[k] != vn){ l = -INFINITY; }
    else {
      const float* kr = qkv + (size_t)k*384 + 128 + h*16;
      l = 0.f;
      #pragma unroll
      for (int d=0; d<16; ++d) l = fmaf(qh[d], kr[d], l);
    }
    float mn = fmaxf(m, l);
    float ea = (m > -3.0e38f) ? __expf(m - mn) : 0.f;
    float p  = (l > -3.0e38f) ? __expf(l - mn) : 0.f;
    s = s*ea + p;
    const float* vr = qkv + (size_t)k*384 + 256 + h*16;
    #pragma unroll
    for (int d=0; d<16; ++d) o[d] = o[d]*ea + p*vr[d];
    m = mn;
  }
  mergeW<16>(m, s, o);
  if (j == 0){
    float inv = (s > 0.f) ? 1.f/s : 0.f;
    #pragma unroll
    for (int d=0; d<16; ++d) att[h*16 + d] = o[d]*inv;
  }
  __syncthreads();
  float acc = ld(bias, bOff + t, bf);
  for (int k = 0; k < 128; ++k) acc = fmaf(att[k], ld(W, wOff + (long)k*128 + t, bf), acc);
  float v = q[(size_t)n*128 + t] + acc;
  red[t] = v; __syncthreads();
  for (int off=64; off; off>>=1){ if (t<off) red[t]+=red[t+off]; __syncthreads(); }
  float mean = red[0]*(1.f/128.f);
  __syncthreads();
  float d = v - mean;
  red[t] = d*d; __syncthreads();
  for (int off=64; off; off>>=1){ if (t<off) red[t]+=red[t+off]; __syncthreads(); }
  float var = red[0]*(1.f/128.f);
  float r = rsqrtf(var + 1e-5f);
  q[(size_t)n*128 + t] = d*r*ld(g,gOff+t,bf) + ld(b,bOff2+t,bf);
}

// ================= cross-attention: view-shared LDS-staged partial =================
// grid (NC, 4 head-pairs, 6 views), block 256 = 8 groups of 32 lanes
__global__ __launch_bounds__(256) void k_cross_part(
    const float* __restrict__ qca, const bf16* __restrict__ kh, const bf16* __restrict__ vh,
    const float* __restrict__ fpos, const float* __restrict__ ctr,
    const float* __restrict__ is2p, const int* __restrict__ view,
    float* __restrict__ pm, float* __restrict__ ps, float* __restrict__ po){
  __shared__ __align__(16) unsigned short KV[2][2][CK][20]; // [k/v][h2][key][16+4pad]
  __shared__ float2 fp[CK];
  __shared__ int qlist[200];
  __shared__ int qcnt;
  int ch = blockIdx.x, hp = blockIdx.y, v = blockIdx.z;
  int t = threadIdx.x;
  int k0 = ch*CK;
  if (t == 0) qcnt = 0;
  // stage K/V: per (k/v, h2): 224*16 bf16 = 224*4 uint2
  #pragma unroll
  for (int kv = 0; kv < 2; ++kv)
    #pragma unroll
    for (int h2 = 0; h2 < 2; ++h2){
      const bf16* src = (kv ? vh : kh) + ((size_t)(v*8 + hp*2 + h2)*5600 + k0)*16;
      const uint2* s2 = (const uint2*)src;
      for (int i = t; i < CK*4; i += 256){
        int key = i >> 2, part = i & 3;
        *(uint2*)&KV[kv][h2][key][part*4] = s2[i];
      }
    }
  if (t < CK) fp[t] = ((const float2*)fpos)[k0 + t];
  __syncthreads();
  if (t < 200 && view[t] == v){ int i = atomicAdd(&qcnt, 1); qlist[i] = t; }
  __syncthreads();
  int npairs = qcnt*2;
  int g = t >> 5, j = t & 31;
  for (int p = g; p < npairs; p += 8){
    int n = qlist[p >> 1];
    int h2 = p & 1;
    int h = hp*2 + h2;
    float cx = ctr[2*n], cy = ctr[2*n+1];
    float is2 = is2p[n];
    float qh[16];
    const float* qrow = qca + (size_t)n*128 + h*16;
    #pragma unroll
    for (int d=0; d<16; ++d) qh[d] = qrow[d] * 0.25f;
    float m = -INFINITY, s = 0.f, o[16];
    #pragma unroll
    for (int d=0; d<16; ++d) o[d]=0.f;
    #pragma unroll 2
    for (int i = 0; i < CK/32; ++i){
      int key = i*32 + j;
      float2 pxy = fp[key];
      float dx = cx - pxy.x, dy = cy - pxy.y;
      float gg = -(dx*dx + dy*dy) * is2;
      const uint2* kp = (const uint2*)&KV[0][h2][key][0];
      const uint2* vp = (const uint2*)&KV[1][h2][key][0];
      float kf[16], vf[16];
      #pragma unroll
      for (int u=0; u<4; ++u){
        uint2 a = kp[u]; unpack2(a.x, kf+u*4); unpack2(a.y, kf+u*4+2);
        uint2 b = vp[u]; unpack2(b.x, vf+u*4); unpack2(b.y, vf+u*4+2);
      }
      float l = gg;
      #pragma unroll
      for (int d=0; d<16; ++d) l = fmaf(qh[d], kf[d], l);
      l = (gg < LOG_EPS) ? -INFINITY : l;
      float mn = fmaxf(m, l);
      float ea = (m > -3.0e38f) ? __expf(m - mn) : 0.f;
      float pr = (l > -3.0e38f) ? __expf(l - mn) : 0.f;
      s = s*ea + pr;
      #pragma unroll
      for (int d=0; d<16; ++d) o[d] = o[d]*ea + pr*vf[d];
      m = mn;
    }
    mergeW<32>(m, s, o);
    if (j == 0){
      int idx = (n*NC + ch)*8 + h;
      pm[idx] = m; ps[idx] = s;
      float4* o4 = (float4*)(po + (size_t)idx*16);
      o4[0] = make_float4(o[0],o[1],o[2],o[3]);
      o4[1] = make_float4(o[4],o[5],o[6],o[7]);
      o4[2] = make_float4(o[8],o[9],o[10],o[11]);
      o4[3] = make_float4(o[12],o[13],o[14],o[15]);
    }
  }
}

// ================= cross-attention: merge + out-proj + LN =================
__global__ __launch_bounds__(128) void k_cross_fin(
    const float* __restrict__ pm, const float* __restrict__ ps, const float* __restrict__ po,
    const void* __restrict__ W, long wOff, const void* __restrict__ bias, long bOff,
    float* __restrict__ q, const void* __restrict__ g, long gOff,
    const void* __restrict__ b, long bOff2, const int* __restrict__ flg){
  __shared__ float att[128];
  __shared__ float red[128];
  int bf = *flg;
  int n = blockIdx.x, t = threadIdx.x;
  int h = t >> 4, d = t & 15;
  float m = -INFINITY, s = 0.f, o = 0.f;
  for (int c = 0; c < NC; ++c){
    int idx = (n*NC + c)*8 + h;
    float mc = pm[idx], sc = ps[idx], oc = po[(size_t)idx*16 + d];
    float mn = fmaxf(m, mc);
    float ea = (m  > -3.0e38f) ? __expf(m  - mn) : 0.f;
    float eb = (mc > -3.0e38f) ? __expf(mc - mn) : 0.f;
    s = s*ea + sc*eb;
    o = o*ea + oc*eb;
    m = mn;
  }
  att[h*16 + d] = (s > 0.f) ? o/s : 0.f;
  __syncthreads();
  float acc = ld(bias, bOff + t, bf);
  for (int k = 0; k < 128; ++k) acc = fmaf(att[k], ld(W, wOff + (long)k*128 + t, bf), acc);
  float v = q[(size_t)n*128 + t] + acc;
  red[t] = v; __syncthreads();
  for (int off=64; off; off>>=1){ if (t<off) red[t]+=red[t+off]; __syncthreads(); }
  float mean = red[0]*(1.f/128.f);
  __syncthreads();
  float dd = v - mean;
  red[t] = dd*dd; __syncthreads();
  for (int off=64; off; off>>=1){ if (t<off) red[t]+=red[t+off]; __syncthreads(); }
  float var = red[0]*(1.f/128.f);
  float r = rsqrtf(var + 1e-5f);
  q[(size_t)n*128 + t] = dd*r*ld(g,gOff+t,bf) + ld(b,bOff2+t,bf);
}

// ================= fused FFN =================
__global__ __launch_bounds__(256) void k_ffn(
    float* __restrict__ q,
    const void* __restrict__ w1, long w1o, const void* __restrict__ b1, long b1o,
    const void* __restrict__ w2, long w2o, const void* __restrict__ b2, long b2o,
    const void* __restrict__ g, long go, const void* __restrict__ bb, long bbo,
    const int* __restrict__ flg){
  __shared__ float xs[128];
  __shared__ float hs[256];
  __shared__ float red[128];
  int bf = *flg;
  int n = blockIdx.x, t = threadIdx.x;
  if (t < 128) xs[t] = q[(size_t)n*128 + t];
  __syncthreads();
  float a = ld(b1, b1o + t, bf);
  for (int k = 0; k < 128; ++k) a = fmaf(xs[k], ld(w1, w1o + (long)k*256 + t, bf), a);
  hs[t] = fmaxf(a, 0.f);
  __syncthreads();
  float v = 0.f;
  if (t < 128){
    float acc = ld(b2, b2o + t, bf);
    for (int k = 0; k < 256; ++k) acc = fmaf(hs[k], ld(w2, w2o + (long)k*128 + t, bf), acc);
    v = xs[t] + acc;
    red[t] = v;
  }
  __syncthreads();
  for (int off=64; off; off>>=1){ if (t<off) red[t]+=red[t+off]; __syncthreads(); }
  float mean = red[0]*(1.f/128.f);
  __syncthreads();
  float d = v - mean;
  if (t < 128) red[t] = d*d;
  __syncthreads();
  for (int off=64; off; off>>=1){ if (t<off) red[t]+=red[t+off]; __syncthreads(); }
  float var = red[0]*(1.f/128.f);
  float r = rsqrtf(var + 1e-5f);
  if (t < 128)
    q[(size_t)n*128 + t] = d*r*ld(g,go+t,bf) + ld(bb,bbo+t,bf);
}

// ================= fused pred head =================
__global__ __launch_bounds__(128) void k_pred_full(
    const void* __restrict__ iqf, float* __restrict__ q,
    const void* __restrict__ pw1, const void* __restrict__ pb1,
    const void* __restrict__ pw2, const void* __restrict__ pb2,
    const void* __restrict__ niqp, void* __restrict__ out, long outOff,
    float* __restrict__ is2p, int mode, const int* __restrict__ flg){
  __shared__ float xs[128];
  __shared__ float acc[6*128];
  __shared__ float bbv[8];
  int bf = *flg;
  int n = blockIdx.x, t = threadIdx.x;
  float xv;
  if (mode == 0){
    xv = ld(iqf, (long)t*200 + n, bf);
    q[(size_t)n*128 + t] = xv;
  } else {
    xv = q[(size_t)n*128 + t];
  }
  xs[t] = xv;
  __syncthreads();
  float a = ld(pb1, t, bf);
  for (int k = 0; k < 128; ++k) a = fmaf(xs[k], ld(pw1, (long)k*128 + t, bf), a);
  float x = fmaxf(a, 0.f);
  #pragma unroll
  for (int c=0;c<6;++c) acc[c*128+t] = x * ld(pw2, t*6 + c, bf);
  __syncthreads();
  for (int off=64; off; off>>=1){
    if (t < off){
      #pragma unroll
      for (int c=0;c<6;++c) acc[c*128+t] += acc[c*128+t+off];
    }
    __syncthreads();
  }
  if (t < 6){
    float raw = acc[t*128] + ld(pb2, t, bf);
    if (mode == 1){
      if (t < 2) raw += ld(niqp, 2*n + t, bf);
      float sv = sigm(raw);
      st(out, outOff + n*6 + t, sv, bf);
      bbv[t] = sv;
    } else {
      bbv[t] = raw;
    }
  }
  __syncthreads();
  if (t == 0){
    float dxv = sigm(bbv[2]) * IMGX;
    float dyv = sigm(bbv[3]) * IMGY;
    float rad = ceilf(sqrtf(dxv*dxv + dyv*dyv) * 0.5f);
    float sg = (rad*2.f + 1.f) * (1.f/6.f);
    is2p[n] = 1.f/(2.f*sg*sg);
  }
}

__global__ void k_write_q(const float* __restrict__ q, void* __restrict__ out,
                          const int* __restrict__ flg){
  int bf = *flg;
  int idx = blockIdx.x*blockDim.x + threadIdx.x;
  if (idx >= 25600) return;
  int c = idx / 200, n = idx % 200;
  st(out, idx, q[(size_t)n*128 + c], bf);
}

// ================= launch =================
extern "C" void kernel_launch(void* const* d_in, const int* in_sizes, int n_in,
                              void* d_out, int out_size, void* d_ws, size_t ws_size,
                              hipStream_t stream){
  const void* iqf   = d_in[0];
  const void* niqp  = d_in[1];
  const void* iff   = d_in[2];
  const void* nifp  = d_in[3];
  const void* l2i   = d_in[4];
  const int*  view  = (const int*)d_in[5];
  const void* sa_qkv_w = d_in[6];
  const void* sa_qkv_b = d_in[7];
  const void* sa_out_w = d_in[8];
  const void* sa_out_b = d_in[9];
  const void* ca_qkv_w = d_in[10];
  const void* ca_qkv_b = d_in[11];
  const void* ca_out_w = d_in[12];
  const void* ca_out_b = d_in[13];
  const void* ln1_g = d_in[14];
  const void* ln1_b = d_in[15];
  const void* ln2_g = d_in[16];
  const void* ln2_b = d_in[17];
  const void* ln3_g = d_in[18];
  const void* ln3_b = d_in[19];
  const void* ffn_w1 = d_in[20];
  const void* ffn_b1 = d_in[21];
  const void* ffn_w2 = d_in[22];
  const void* ffn_b2 = d_in[23];
  const void* qpos_w1 = d_in[24];
  const void* qpos_b1 = d_in[25];
  const void* qpos_w2 = d_in[26];
  const void* qpos_b2 = d_in[27];
  const void* kpos_w1 = d_in[28];
  const void* kpos_b1 = d_in[29];
  const void* kpos_w2 = d_in[30];
  const void* kpos_b2 = d_in[31];
  const void* pred_w1 = d_in[32];
  const void* pred_b1 = d_in[33];
  const void* pred_w2 = d_in[34];
  const void* pred_b2 = d_in[35];

  float* fw = (float*)d_ws;
  float* q    = fw + OFF_Q;
  float* qpe  = fw + OFF_QPE;
  float* tmp  = fw + OFF_TMP;
  float* kpe  = fw + OFF_KPE;
  float* pm   = fw + OFF_PM;
  float* ps   = fw + OFF_PS;
  float* po   = fw + OFF_PO;
  float* fpos = fw + OFF_FPOS;
  float* ctr  = fw + OFF_CTR;
  float* sig2 = fw + OFF_SIG;
  int*   flg  = (int*)(fw + OFF_FLAG);
  bf16* bw   = (bf16*)((char*)d_ws + F_TOTAL*sizeof(float));
  bf16* keys = bw + B_KEYS;
  bf16* kh   = bw + B_KH;
  bf16* vh   = bw + B_VH;

  k_probe<<<1, 1, 0, stream>>>(ln1_g, flg);
  k_transpose<<<dim3(175,4,6), dim3(32,8), 0, stream>>>(iff, keys, flg);
  k_feat_pos<<<22, 256, 0, stream>>>(nifp, fpos, flg);
  k_prep<<<200, 64, 0, stream>>>(niqp, l2i, view, ctr, d_out, flg);
  k_pred_full<<<200, 128, 0, stream>>>(iqf, q, pred_w1, pred_b1, pred_w2, pred_b2,
                                       niqp, nullptr, 0, sig2, 0, flg);

  for (int l = 0; l < 2; ++l){
    // kpe (5600,128) via MFMA; qpe (200,128) small fused MLP
    k_kpe_mfma<<<88, 256, 0, stream>>>(nifp, kpos_w1, l*256L, kpos_b1, l*128L,
                                       kpos_w2, l*16384L, kpos_b2, l*128L, kpe, flg);
    k_posembed_f<<<200, 128, 0, stream>>>(niqp, qpos_w1, l*256L, qpos_b1, l*128L,
                                          qpos_w2, l*16384L, qpos_b2, l*128L, qpe, flg);
    // self-attention
    k_linear<0><<<200, 384, 0, stream>>>(q, qpe, sa_qkv_w, l*49152L, 384, sa_qkv_b, l*384L, tmp, 128, 384, flg);
    k_self_attn_f<<<200, 128, 0, stream>>>(tmp, view, sa_out_w, l*16384L, sa_out_b, l*128L,
                                           q, ln1_g, l*128L, ln1_b, l*128L, flg);
    // cross-attention
    k_linear<0><<<200, 128, 0, stream>>>(q, qpe, ca_qkv_w, l*49152L, 384, ca_qkv_b, l*384L, tmp, 128, 128, flg);
    k_kv_proj_mfma<<<525, 256, 0, stream>>>(keys, kpe, ca_qkv_w, l*49152L, ca_qkv_b, l*384L, kh, vh, flg);
    k_cross_part<<<dim3(NC,4,6), 256, 0, stream>>>(tmp, kh, vh, fpos, ctr, sig2, view, pm, ps, po);
    k_cross_fin<<<200, 128, 0, stream>>>(pm, ps, po, ca_out_w, l*16384L, ca_out_b, l*128L,
                                         q, ln2_g, l*128L, ln2_b, l*128L, flg);
    // FFN
    k_ffn<<<200, 256, 0, stream>>>(q, ffn_w1, l*32768L, ffn_b1, l*256L,
                                   ffn_w2, l*32768L, ffn_b2, l*128L,
                                   ln3_g, l*128L, ln3_b, l*128L, flg);
    // pred head
    k_pred_full<<<200, 128, 0, stream>>>(nullptr, q, pred_w1, pred_b1, pred_w2, pred_b2,
                                         niqp, d_out, (l==0 ? 45200L : 46400L), sig2, 1, flg);
  }
  k_write_q<<<100, 256, 0, stream>>>(q, d_out, flg);
}

// Round 6
// 599.874 us; speedup vs baseline: 1.0585x; 1.0585x over previous
//
#include <hip/hip_runtime.h>
#include <hip/hip_bf16.h>
#include <cstdint>
#include <cstddef>

using bf16 = __hip_bfloat16;
#define DEV __device__ __forceinline__

typedef short s16x8 __attribute__((ext_vector_type(8)));
typedef float f32x4 __attribute__((ext_vector_type(4)));

DEV float b2f(bf16 x){ return __bfloat162float(x); }
DEV bf16  f2b(float x){ return __float2bfloat16(x); }
DEV float u2f(unsigned u){ union{unsigned u; float f;} c; c.u=u; return c.f; }
DEV unsigned f2u(float f){ union{float f; unsigned u;} c; c.f=f; return c.u; }
DEV unsigned short f2bu(float f){ unsigned u = f2u(f); u += 0x7FFFu + ((u>>16)&1u); return (unsigned short)(u>>16); }
DEV float sigm(float x){ return 1.f/(1.f+__expf(-x)); }

// dtype flag derived in-kernel: ln1_g is all-ones; bf16 pair = 0x3F803F80
DEV int get_bf(const void* ln1g){ return ((*(const unsigned*)ln1g) & 0xFFFFu) == 0x3F80u; }

DEV float ld(const void* p, long i, int bf){
  return bf ? b2f(((const bf16*)p)[i]) : ((const float*)p)[i];
}
DEV void st(void* p, long i, float v, int bf){
  if (bf) ((bf16*)p)[i] = f2b(v); else ((float*)p)[i] = v;
}

constexpr float IMGX = 100.0f;
constexpr float IMGY = 56.0f;
constexpr float LOG_EPS = -15.942385f;
constexpr float BIN = 53.0f/1056.0f;
constexpr int NC = 35;        // key chunks
constexpr int CK = 160;       // keys per chunk (5600 = 35*160)

// ---- workspace layout (float units) ----
constexpr size_t OFF_Q    = 0;        // 200*128
constexpr size_t OFF_QPE  = 25600;    // 200*128
constexpr size_t OFF_QCA  = 51200;    // 200*128
constexpr size_t OFF_TMP  = 76800;    // 200*384
constexpr size_t OFF_PM   = 153600;   // 200*35*8
constexpr size_t OFF_PS   = 209600;   // 200*35*8
constexpr size_t OFF_PO   = 265600;   // 200*35*8*16
constexpr size_t OFF_FPOS = 1161600;  // 5600*2
constexpr size_t OFF_CTR  = 1172800;  // 200*2
constexpr size_t OFF_SIG  = 1173200;  // 200
constexpr size_t F_TOTAL  = 1173408;
// bf16 region after floats:
constexpr size_t B_KEYS = 0;          // 33600*128
constexpr size_t B_KH   = 4300800;    // 6*8*5600*16
constexpr size_t B_VH   = 8601600;
constexpr size_t B_KPE  = 12902400;   // 5600*128

DEV void unpack2(unsigned u, float* f){ f[0]=u2f(u<<16); f[1]=u2f(u&0xffff0000u); }

template<int W>
DEV void mergeW(float& m, float& s, float (&o)[16]){
  #pragma unroll
  for (int off=W/2; off>=1; off>>=1){
    float m2 = __shfl_xor(m, off);
    float s2 = __shfl_xor(s, off);
    float mn = fmaxf(m, m2);
    float ea = (m  > -3.0e38f) ? __expf(m  - mn) : 0.f;
    float eb = (m2 > -3.0e38f) ? __expf(m2 - mn) : 0.f;
    s = s*ea + s2*eb;
    #pragma unroll
    for (int d=0; d<16; ++d){
      float od = __shfl_xor(o[d], off);
      o[d] = o[d]*ea + od*eb;
    }
    m = mn;
  }
}

// ================= prep =================
__global__ void k_transpose(const void* __restrict__ iff, bf16* __restrict__ keys,
                            const void* __restrict__ ln1g){
  __shared__ float t[32][33];
  int bf = get_bf(ln1g);
  int k0 = blockIdx.x*32, c0 = blockIdx.y*32, v = blockIdx.z;
  int tx = threadIdx.x, ty = threadIdx.y;
  #pragma unroll
  for (int i=0;i<4;++i){
    int c = c0 + ty + i*8;
    t[ty+i*8][tx] = ld(iff, (long)(v*128 + c)*5600 + k0 + tx, bf);
  }
  __syncthreads();
  #pragma unroll
  for (int i=0;i<4;++i){
    int k = k0 + ty + i*8;
    keys[(size_t)(v*5600 + k)*128 + c0 + tx] = f2b(t[tx][ty+i*8]);
  }
}

__global__ void k_feat_pos(const void* __restrict__ nifp, float* __restrict__ fpos,
                           const void* __restrict__ ln1g){
  int bf = get_bf(ln1g);
  int k = blockIdx.x*blockDim.x + threadIdx.x;
  if (k >= 5600) return;
  fpos[2*k]   = sigm(ld(nifp,2*k,bf))*IMGX - 0.5f;
  fpos[2*k+1] = sigm(ld(nifp,2*k+1,bf))*IMGY - 0.5f;
}

__global__ __launch_bounds__(64) void k_prep(
    const void* __restrict__ niqp, const void* __restrict__ l2i,
    const int* __restrict__ view, float* __restrict__ ctr,
    void* __restrict__ out, const void* __restrict__ ln1g){
  __shared__ float M[16];
  __shared__ float cs[2];
  int bf = get_bf(ln1g);
  int n = blockIdx.x, t = threadIdx.x;
  if (t == 0){
    float p0 = ld(niqp,2*n,bf), p1 = ld(niqp,2*n+1,bf);
    float cx = sigm(p0)*IMGX, cy = sigm(p1)*IMGY;
    ctr[2*n] = cx; ctr[2*n+1] = cy;
    cs[0] = cx; cs[1] = cy;
    st(out, 25600 + 2*n,   p0, bf);
    st(out, 25600 + 2*n+1, p1, bf);
    int v = view[n];
    float a[4][8];
    for (int i=0;i<4;++i)
      for (int j=0;j<4;++j){ a[i][j] = ld(l2i, v*16+i*4+j, bf); a[i][4+j] = (i==j)?1.f:0.f; }
    for (int col=0; col<4; ++col){
      int p = col; float best = fabsf(a[col][col]);
      for (int r=col+1;r<4;++r){ float tt=fabsf(a[r][col]); if (tt>best){best=tt;p=r;} }
      if (p!=col) for (int j=0;j<8;++j){ float tt=a[col][j]; a[col][j]=a[p][j]; a[p][j]=tt; }
      float inv = 1.f/a[col][col];
      for (int j=0;j<8;++j) a[col][j]*=inv;
      for (int r=0;r<4;++r){
        if (r==col) continue;
        float f = a[r][col];
        for (int j=0;j<8;++j) a[r][j] -= f*a[col][j];
      }
    }
    for (int i=0;i<4;++i) for (int j=0;j<4;++j) M[i*4+j] = a[i][4+j];
  }
  __syncthreads();
  if (t < 32){
    int d = t;
    float px = cs[0]*8.f, py = cs[1]*8.f;
    float dep = 1.f + BIN * (float)d * (float)(d+1);
    float x = px*dep, y = py*dep;
    #pragma unroll
    for (int i=0;i<3;++i){
      float val = M[i*4]*x + M[i*4+1]*y + M[i*4+2]*dep + M[i*4+3];
      st(out, 26000 + n*96 + d*3 + i, val, bf);
    }
  }
}

// init q from iqf^T + pre-loop pred for sigma
__global__ __launch_bounds__(128) void k_pred0(
    const void* __restrict__ iqf, float* __restrict__ q,
    const void* __restrict__ pw1, const void* __restrict__ pb1,
    const void* __restrict__ pw2, const void* __restrict__ pb2,
    float* __restrict__ is2p, const void* __restrict__ ln1g){
  __shared__ float xs[128];
  __shared__ float acc[6*128];
  __shared__ float bbv[8];
  int bf = get_bf(ln1g);
  int n = blockIdx.x, t = threadIdx.x;
  float xv = ld(iqf, (long)t*200 + n, bf);
  q[(size_t)n*128 + t] = xv;
  xs[t] = xv;
  __syncthreads();
  float a = ld(pb1, t, bf);
  for (int k = 0; k < 128; ++k) a = fmaf(xs[k], ld(pw1, (long)k*128 + t, bf), a);
  float x = fmaxf(a, 0.f);
  #pragma unroll
  for (int c=0;c<6;++c) acc[c*128+t] = x * ld(pw2, t*6 + c, bf);
  __syncthreads();
  for (int off=64; off; off>>=1){
    if (t < off){
      #pragma unroll
      for (int c=0;c<6;++c) acc[c*128+t] += acc[c*128+t+off];
    }
    __syncthreads();
  }
  if (t < 6) bbv[t] = acc[t*128] + ld(pb2, t, bf);
  __syncthreads();
  if (t == 0){
    float dxv = sigm(bbv[2]) * IMGX;
    float dyv = sigm(bbv[3]) * IMGY;
    float rad = ceilf(sqrtf(dxv*dxv + dyv*dyv) * 0.5f);
    float sg = (rad*2.f + 1.f) * (1.f/6.f);
    is2p[n] = 1.f/(2.f*sg*sg);
  }
}

// ================= kpe via MFMA (output bf16) =================
__global__ __launch_bounds__(256) void k_kpe_mfma(
    const void* __restrict__ nifp,
    const void* __restrict__ w1, long w1o, const void* __restrict__ b1, long b1o,
    const void* __restrict__ w2, long w2o, const void* __restrict__ b2, long b2o,
    bf16* __restrict__ kpe, const void* __restrict__ ln1g){
  constexpr int XP = 136;
  __shared__ __align__(16) unsigned short xs[64*XP];
  __shared__ float2 pr[64];
  int bf = get_bf(ln1g);
  int r0 = blockIdx.x * 64;
  int tid = threadIdx.x;
  if (tid < 64){
    int k = r0 + tid; if (k > 5599) k = 5599;
    pr[tid] = make_float2(ld(nifp,2*k,bf), ld(nifp,2*k+1,bf));
  }
  __syncthreads();
  for (int idx = tid; idx < 64*64; idx += 256){
    int r = idx >> 6, c2 = (idx & 63)*2;
    float2 p = pr[r];
    #pragma unroll
    for (int u=0;u<2;++u){
      int c = c2+u;
      float a = fmaf(p.x, ld(w1,w1o+c,bf), fmaf(p.y, ld(w1,w1o+128+c,bf), ld(b1,b1o+c,bf)));
      xs[r*XP + c] = f2bu(fmaxf(a, 0.f));
    }
  }
  int wv = tid >> 6;
  int lane = tid & 63;
  int l16 = lane & 15, quad = lane >> 4;
  f32x4 acc[4][2];
  #pragma unroll
  for (int mt=0;mt<4;++mt)
    #pragma unroll
    for (int nt=0;nt<2;++nt) acc[mt][nt] = (f32x4){0.f,0.f,0.f,0.f};
  __syncthreads();
  #pragma unroll
  for (int kc = 0; kc < 4; ++kc){
    s16x8 bfr[2];
    #pragma unroll
    for (int nt = 0; nt < 2; ++nt){
      long base = w2o + (long)(kc*32 + quad*8)*128 + (wv*32 + nt*16 + l16);
      s16x8 bb;
      #pragma unroll
      for (int j = 0; j < 8; ++j) bb[j] = (short)f2bu(ld(w2, base + (long)j*128, bf));
      bfr[nt] = bb;
    }
    s16x8 afr[4];
    #pragma unroll
    for (int mt = 0; mt < 4; ++mt)
      afr[mt] = *(const s16x8*)&xs[(mt*16 + l16)*XP + kc*32 + quad*8];
    #pragma unroll
    for (int mt = 0; mt < 4; ++mt)
      #pragma unroll
      for (int nt = 0; nt < 2; ++nt)
        acc[mt][nt] = __builtin_amdgcn_mfma_f32_16x16x32_bf16(afr[mt], bfr[nt], acc[mt][nt], 0, 0, 0);
  }
  float bv[2];
  #pragma unroll
  for (int nt=0;nt<2;++nt) bv[nt] = ld(b2, b2o + wv*32 + nt*16 + l16, bf);
  #pragma unroll
  for (int mt = 0; mt < 4; ++mt)
    #pragma unroll
    for (int i = 0; i < 4; ++i){
      int gr = r0 + mt*16 + quad*4 + i;
      if (gr < 5600){
        #pragma unroll
        for (int nt = 0; nt < 2; ++nt)
          kpe[(size_t)gr*128 + wv*32 + nt*16 + l16] = f2b(acc[mt][nt][i] + bv[nt]);
      }
    }
}

// ================= fused qpe + sa_qkv projection =================
// block 384 threads: t<128 computes qpe (stores to qpe_g), then all compute qkv col t
__global__ __launch_bounds__(384) void k_saqkv(
    const float* __restrict__ q, const void* __restrict__ niqp,
    const void* __restrict__ w1, long w1o, const void* __restrict__ b1, long b1o,
    const void* __restrict__ w2, long w2o, const void* __restrict__ b2, long b2o,
    const void* __restrict__ qkvw, long qwo, const void* __restrict__ qkvb, long qbo,
    float* __restrict__ qpe_g, float* __restrict__ tmp, const void* __restrict__ ln1g){
  __shared__ float hs[128];
  __shared__ float xq[128];
  int bf = get_bf(ln1g);
  int n = blockIdx.x, t = threadIdx.x;
  if (t < 128){
    float p0 = ld(niqp,2*n,bf), p1 = ld(niqp,2*n+1,bf);
    float a = fmaf(p0, ld(w1,w1o+t,bf), fmaf(p1, ld(w1,w1o+128+t,bf), ld(b1,b1o+t,bf)));
    hs[t] = fmaxf(a, 0.f);
  }
  __syncthreads();
  if (t < 128){
    float a = ld(b2, b2o+t, bf);
    for (int k = 0; k < 128; ++k) a = fmaf(hs[k], ld(w2, w2o + (long)k*128 + t, bf), a);
    qpe_g[(size_t)n*128 + t] = a;
    xq[t] = q[(size_t)n*128 + t] + a;
  }
  __syncthreads();
  float acc = ld(qkvb, qbo + t, bf);
  for (int k = 0; k < 128; ++k) acc = fmaf(xq[k], ld(qkvw, qwo + (long)k*384 + t, bf), acc);
  tmp[(size_t)n*384 + t] = acc;
}

// ================= self-attn + out-proj + LN1 + ca-q projection =================
__global__ __launch_bounds__(128) void k_self_attn_f(
    const float* __restrict__ qkv, const int* __restrict__ view,
    const void* __restrict__ W, long wOff, const void* __restrict__ bias, long bOff,
    float* __restrict__ q, const void* __restrict__ g, long gOff,
    const void* __restrict__ b, long bOff2,
    const float* __restrict__ qpe_g,
    const void* __restrict__ caw, long cawo, const void* __restrict__ cab, long cabo,
    float* __restrict__ qca, const void* __restrict__ ln1g){
  __shared__ float att[128];
  __shared__ float red[128];
  __shared__ float xs2[128];
  int bf = get_bf(ln1g);
  int n = blockIdx.x, t = threadIdx.x;
  int h = t >> 4, j = t & 15;
  int vn = view[n];
  float qh[16];
  #pragma unroll
  for (int d=0; d<16; ++d) qh[d] = qkv[(size_t)n*384 + h*16 + d] * 0.25f;
  float m = -INFINITY, s = 0.f, o[16];
  #pragma unroll
  for (int d=0; d<16; ++d) o[d]=0.f;
  for (int k = j; k < 200; k += 16){
    float l;
    if (view[k] != vn){ l = -INFINITY; }
    else {
      const float* kr = qkv + (size_t)k*384 + 128 + h*16;
      l = 0.f;
      #pragma unroll
      for (int d=0; d<16; ++d) l = fmaf(qh[d], kr[d], l);
    }
    float mn = fmaxf(m, l);
    float ea = (m > -3.0e38f) ? __expf(m - mn) : 0.f;
    float p  = (l > -3.0e38f) ? __expf(l - mn) : 0.f;
    s = s*ea + p;
    const float* vr = qkv + (size_t)k*384 + 256 + h*16;
    #pragma unroll
    for (int d=0; d<16; ++d) o[d] = o[d]*ea + p*vr[d];
    m = mn;
  }
  mergeW<16>(m, s, o);
  if (j == 0){
    float inv = (s > 0.f) ? 1.f/s : 0.f;
    #pragma unroll
    for (int d=0; d<16; ++d) att[h*16 + d] = o[d]*inv;
  }
  __syncthreads();
  float acc = ld(bias, bOff + t, bf);
  for (int k = 0; k < 128; ++k) acc = fmaf(att[k], ld(W, wOff + (long)k*128 + t, bf), acc);
  float v = q[(size_t)n*128 + t] + acc;
  red[t] = v; __syncthreads();
  for (int off=64; off; off>>=1){ if (t<off) red[t]+=red[t+off]; __syncthreads(); }
  float mean = red[0]*(1.f/128.f);
  __syncthreads();
  float d = v - mean;
  red[t] = d*d; __syncthreads();
  for (int off=64; off; off>>=1){ if (t<off) red[t]+=red[t+off]; __syncthreads(); }
  float var = red[0]*(1.f/128.f);
  float r = rsqrtf(var + 1e-5f);
  float qn = d*r*ld(g,gOff+t,bf) + ld(b,bOff2+t,bf);
  q[(size_t)n*128 + t] = qn;
  xs2[t] = qn + qpe_g[(size_t)n*128 + t];
  __syncthreads();
  float a2 = ld(cab, cabo + t, bf);
  for (int k = 0; k < 128; ++k) a2 = fmaf(xs2[k], ld(caw, cawo + (long)k*384 + t, bf), a2);
  qca[(size_t)n*128 + t] = a2;
}

// ================= K/V projection — MFMA =================
__global__ __launch_bounds__(256) void k_kv_proj_mfma(
    const bf16* __restrict__ keys, const bf16* __restrict__ kpe,
    const void* __restrict__ W, long wOff, const void* __restrict__ bias, long bOff,
    bf16* __restrict__ kh, bf16* __restrict__ vh, const void* __restrict__ ln1g){
  constexpr int XP = 136;
  __shared__ __align__(16) unsigned short xs[64*XP];
  int bf = get_bf(ln1g);
  int r0 = blockIdx.x * 64;
  int tid = threadIdx.x;
  for (int idx = tid; idx < 64*64; idx += 256){
    int r = idx >> 6, c2 = (idx & 63)*2;
    int gr = r0 + r;
    int v = gr / 5600; int k = gr - v*5600;
    float a0 = b2f(keys[(size_t)gr*128 + c2])   + b2f(kpe[(size_t)k*128 + c2]);
    float a1 = b2f(keys[(size_t)gr*128 + c2+1]) + b2f(kpe[(size_t)k*128 + c2+1]);
    xs[r*XP + c2]   = f2bu(a0);
    xs[r*XP + c2+1] = f2bu(a1);
  }
  int wv = tid >> 6;
  int lane = tid & 63;
  int l16 = lane & 15, quad = lane >> 4;
  f32x4 acc[4][4];
  #pragma unroll
  for (int mt=0;mt<4;++mt)
    #pragma unroll
    for (int nt=0;nt<4;++nt) acc[mt][nt] = (f32x4){0.f,0.f,0.f,0.f};
  __syncthreads();
  #pragma unroll
  for (int kc = 0; kc < 4; ++kc){
    s16x8 bfr[4];
    #pragma unroll
    for (int nt = 0; nt < 4; ++nt){
      long base = wOff + (long)(kc*32 + quad*8)*384 + (128 + wv*64 + nt*16 + l16);
      s16x8 bb;
      #pragma unroll
      for (int j = 0; j < 8; ++j) bb[j] = (short)f2bu(ld(W, base + (long)j*384, bf));
      bfr[nt] = bb;
    }
    s16x8 afr[4];
    #pragma unroll
    for (int mt = 0; mt < 4; ++mt)
      afr[mt] = *(const s16x8*)&xs[(mt*16 + l16)*XP + kc*32 + quad*8];
    #pragma unroll
    for (int mt = 0; mt < 4; ++mt)
      #pragma unroll
      for (int nt = 0; nt < 4; ++nt)
        acc[mt][nt] = __builtin_amdgcn_mfma_f32_16x16x32_bf16(afr[mt], bfr[nt], acc[mt][nt], 0, 0, 0);
  }
  float bv[4];
  bf16* op[4];
  long ntOff[4];
  #pragma unroll
  for (int nt = 0; nt < 4; ++nt){
    int c = wv*64 + nt*16 + l16;
    bv[nt] = ld(bias, bOff + 128 + c, bf);
    int sel = c >> 7, ch = c & 127;
    int h = ch >> 4, d = ch & 15;
    op[nt] = sel ? vh : kh;
    ntOff[nt] = (long)h*89600 + d;
  }
  #pragma unroll
  for (int mt = 0; mt < 4; ++mt)
    #pragma unroll
    for (int i = 0; i < 4; ++i){
      int gr = r0 + mt*16 + quad*4 + i;
      int v = gr / 5600; int k = gr - v*5600;
      long rowOff = (long)v*716800 + (long)k*16;
      #pragma unroll
      for (int nt = 0; nt < 4; ++nt)
        op[nt][rowOff + ntOff[nt]] = f2b(acc[mt][nt][i] + bv[nt]);
    }
}

// ================= cross-attention partial: one head/block, interleaved 72B rows =================
// grid (NC, 8 heads, 6 views), block 256 = 8 groups of 32 lanes
__global__ __launch_bounds__(256) void k_cross_part(
    const float* __restrict__ qca, const bf16* __restrict__ kh, const bf16* __restrict__ vh,
    const float* __restrict__ fpos, const float* __restrict__ ctr,
    const float* __restrict__ is2p, const int* __restrict__ view,
    float* __restrict__ pm, float* __restrict__ ps, float* __restrict__ po){
  __shared__ __align__(16) unsigned short KV[CK][36]; // 16 K + 16 V + 4 pad (72B rows)
  __shared__ float2 fp[CK];
  __shared__ int qlist[200];
  __shared__ int qcnt;
  int ch = blockIdx.x, h = blockIdx.y, v = blockIdx.z;
  int t = threadIdx.x;
  int k0 = ch*CK;
  if (t == 0) qcnt = 0;
  const uint2* ks = (const uint2*)(kh + ((size_t)(v*8 + h)*5600 + k0)*16);
  const uint2* vs = (const uint2*)(vh + ((size_t)(v*8 + h)*5600 + k0)*16);
  for (int i = t; i < CK*4; i += 256){
    int key = i >> 2, part = i & 3;
    *(uint2*)&KV[key][part*4]      = ks[i];
    *(uint2*)&KV[key][16 + part*4] = vs[i];
  }
  if (t < CK) fp[t] = ((const float2*)fpos)[k0 + t];
  __syncthreads();
  if (t < 200 && view[t] == v){ int i = atomicAdd(&qcnt, 1); qlist[i] = t; }
  __syncthreads();
  int nq = qcnt;
  int g = t >> 5, j = t & 31;
  for (int p = g; p < nq; p += 8){
    int n = qlist[p];
    float cx = ctr[2*n], cy = ctr[2*n+1];
    float is2 = is2p[n];
    float qh[16];
    const float* qrow = qca + (size_t)n*128 + h*16;
    #pragma unroll
    for (int d=0; d<16; ++d) qh[d] = qrow[d] * 0.25f;
    float m = -INFINITY, s = 0.f, o[16];
    #pragma unroll
    for (int d=0; d<16; ++d) o[d]=0.f;
    #pragma unroll
    for (int i = 0; i < CK/32; ++i){
      int key = i*32 + j;
      float2 pxy = fp[key];
      float dx = cx - pxy.x, dy = cy - pxy.y;
      float gg = -(dx*dx + dy*dy) * is2;
      const uint2* kp = (const uint2*)&KV[key][0];
      const uint2* vp = (const uint2*)&KV[key][16];
      float kf[16], vf[16];
      #pragma unroll
      for (int u=0; u<4; ++u){
        uint2 a = kp[u]; unpack2(a.x, kf+u*4); unpack2(a.y, kf+u*4+2);
        uint2 b = vp[u]; unpack2(b.x, vf+u*4); unpack2(b.y, vf+u*4+2);
      }
      float l = gg;
      #pragma unroll
      for (int d=0; d<16; ++d) l = fmaf(qh[d], kf[d], l);
      l = (gg < LOG_EPS) ? -INFINITY : l;
      float mn = fmaxf(m, l);
      float ea = (m > -3.0e38f) ? __expf(m - mn) : 0.f;
      float pr = (l > -3.0e38f) ? __expf(l - mn) : 0.f;
      s = s*ea + pr;
      #pragma unroll
      for (int d=0; d<16; ++d) o[d] = o[d]*ea + pr*vf[d];
      m = mn;
    }
    mergeW<32>(m, s, o);
    if (j == 0){
      int idx = (n*NC + ch)*8 + h;
      pm[idx] = m; ps[idx] = s;
      float4* o4 = (float4*)(po + (size_t)idx*16);
      o4[0] = make_float4(o[0],o[1],o[2],o[3]);
      o4[1] = make_float4(o[4],o[5],o[6],o[7]);
      o4[2] = make_float4(o[8],o[9],o[10],o[11]);
      o4[3] = make_float4(o[12],o[13],o[14],o[15]);
    }
  }
}

// ================= tail: merge + out-proj + LN2 + FFN + LN3 + pred + bbox =================
__global__ __launch_bounds__(256) void k_tail(
    const float* __restrict__ pm, const float* __restrict__ ps, const float* __restrict__ po,
    const void* __restrict__ cow, long cowo, const void* __restrict__ cob, long cobo,
    float* __restrict__ q,
    const void* __restrict__ g2, long g2o, const void* __restrict__ b2l, long b2lo,
    const void* __restrict__ fw1, long fw1o, const void* __restrict__ fb1, long fb1o,
    const void* __restrict__ fw2, long fw2o, const void* __restrict__ fb2, long fb2o,
    const void* __restrict__ g3, long g3o, const void* __restrict__ b3l, long b3lo,
    const void* __restrict__ pw1, const void* __restrict__ pb1,
    const void* __restrict__ pw2, const void* __restrict__ pb2,
    const void* __restrict__ niqp, void* __restrict__ out, long outOff,
    float* __restrict__ is2p, int last, const void* __restrict__ ln1g){
  __shared__ float att[128];
  __shared__ float red[128];
  __shared__ float xs[128];
  __shared__ float hs[256];
  __shared__ float ac6[6*128];
  __shared__ float bbv[8];
  int bf = get_bf(ln1g);
  int n = blockIdx.x, t = threadIdx.x;
  // --- merge cross partials ---
  if (t < 128){
    int h = t >> 4, d = t & 15;
    float m = -INFINITY, s = 0.f, o = 0.f;
    for (int c = 0; c < NC; ++c){
      int idx = (n*NC + c)*8 + h;
      float mc = pm[idx], sc = ps[idx], oc = po[(size_t)idx*16 + d];
      float mn = fmaxf(m, mc);
      float ea = (m  > -3.0e38f) ? __expf(m  - mn) : 0.f;
      float eb = (mc > -3.0e38f) ? __expf(mc - mn) : 0.f;
      s = s*ea + sc*eb;
      o = o*ea + oc*eb;
      m = mn;
    }
    att[t] = (s > 0.f) ? o/s : 0.f;
  }
  __syncthreads();
  // --- out proj + residual + LN2 ---
  float v = 0.f;
  if (t < 128){
    float acc = ld(cob, cobo + t, bf);
    for (int k = 0; k < 128; ++k) acc = fmaf(att[k], ld(cow, cowo + (long)k*128 + t, bf), acc);
    v = q[(size_t)n*128 + t] + acc;
    red[t] = v;
  }
  __syncthreads();
  for (int off=64; off; off>>=1){ if (t<off) red[t]+=red[t+off]; __syncthreads(); }
  float mean = red[0]*(1.f/128.f);
  __syncthreads();
  float d = v - mean;
  if (t < 128) red[t] = d*d;
  __syncthreads();
  for (int off=64; off; off>>=1){ if (t<off) red[t]+=red[t+off]; __syncthreads(); }
  float var = red[0]*(1.f/128.f);
  float r = rsqrtf(var + 1e-5f);
  if (t < 128) xs[t] = d*r*ld(g2,g2o+t,bf) + ld(b2l,b2lo+t,bf);
  __syncthreads();
  // --- FFN1 (256 cols) ---
  {
    float a = ld(fb1, fb1o + t, bf);
    for (int k = 0; k < 128; ++k) a = fmaf(xs[k], ld(fw1, fw1o + (long)k*256 + t, bf), a);
    hs[t] = fmaxf(a, 0.f);
  }
  __syncthreads();
  // --- FFN2 + residual + LN3 ---
  v = 0.f;
  if (t < 128){
    float acc = ld(fb2, fb2o + t, bf);
    for (int k = 0; k < 256; ++k) acc = fmaf(hs[k], ld(fw2, fw2o + (long)k*128 + t, bf), acc);
    v = xs[t] + acc;
    red[t] = v;
  }
  __syncthreads();
  for (int off=64; off; off>>=1){ if (t<off) red[t]+=red[t+off]; __syncthreads(); }
  mean = red[0]*(1.f/128.f);
  __syncthreads();
  d = v - mean;
  if (t < 128) red[t] = d*d;
  __syncthreads();
  for (int off=64; off; off>>=1){ if (t<off) red[t]+=red[t+off]; __syncthreads(); }
  var = red[0]*(1.f/128.f);
  r = rsqrtf(var + 1e-5f);
  if (t < 128){
    float q3 = d*r*ld(g3,g3o+t,bf) + ld(b3l,b3lo+t,bf);
    q[(size_t)n*128 + t] = q3;
    xs[t] = q3;
    if (last) st(out, (long)t*200 + n, q3, bf);  // q^T output
  }
  __syncthreads();
  // --- pred head ---
  if (t < 128){
    float a = ld(pb1, t, bf);
    for (int k = 0; k < 128; ++k) a = fmaf(xs[k], ld(pw1, (long)k*128 + t, bf), a);
    float x = fmaxf(a, 0.f);
    #pragma unroll
    for (int c=0;c<6;++c) ac6[c*128+t] = x * ld(pw2, t*6 + c, bf);
  }
  __syncthreads();
  for (int off=64; off; off>>=1){
    if (t < off){
      #pragma unroll
      for (int c=0;c<6;++c) ac6[c*128+t] += ac6[c*128+t+off];
    }
    __syncthreads();
  }
  if (t < 6){
    float raw = ac6[t*128] + ld(pb2, t, bf);
    if (t < 2) raw += ld(niqp, 2*n + t, bf);
    float sv = sigm(raw);
    st(out, outOff + n*6 + t, sv, bf);
    bbv[t] = sv;
  }
  __syncthreads();
  if (t == 0){
    float dxv = sigm(bbv[2]) * IMGX;
    float dyv = sigm(bbv[3]) * IMGY;
    float rad = ceilf(sqrtf(dxv*dxv + dyv*dyv) * 0.5f);
    float sg = (rad*2.f + 1.f) * (1.f/6.f);
    is2p[n] = 1.f/(2.f*sg*sg);
  }
}

// ================= launch =================
extern "C" void kernel_launch(void* const* d_in, const int* in_sizes, int n_in,
                              void* d_out, int out_size, void* d_ws, size_t ws_size,
                              hipStream_t stream){
  const void* iqf   = d_in[0];
  const void* niqp  = d_in[1];
  const void* iff   = d_in[2];
  const void* nifp  = d_in[3];
  const void* l2i   = d_in[4];
  const int*  view  = (const int*)d_in[5];
  const void* sa_qkv_w = d_in[6];
  const void* sa_qkv_b = d_in[7];
  const void* sa_out_w = d_in[8];
  const void* sa_out_b = d_in[9];
  const void* ca_qkv_w = d_in[10];
  const void* ca_qkv_b = d_in[11];
  const void* ca_out_w = d_in[12];
  const void* ca_out_b = d_in[13];
  const void* ln1_g = d_in[14];
  const void* ln1_b = d_in[15];
  const void* ln2_g = d_in[16];
  const void* ln2_b = d_in[17];
  const void* ln3_g = d_in[18];
  const void* ln3_b = d_in[19];
  const void* ffn_w1 = d_in[20];
  const void* ffn_b1 = d_in[21];
  const void* ffn_w2 = d_in[22];
  const void* ffn_b2 = d_in[23];
  const void* qpos_w1 = d_in[24];
  const void* qpos_b1 = d_in[25];
  const void* qpos_w2 = d_in[26];
  const void* qpos_b2 = d_in[27];
  const void* kpos_w1 = d_in[28];
  const void* kpos_b1 = d_in[29];
  const void* kpos_w2 = d_in[30];
  const void* kpos_b2 = d_in[31];
  const void* pred_w1 = d_in[32];
  const void* pred_b1 = d_in[33];
  const void* pred_w2 = d_in[34];
  const void* pred_b2 = d_in[35];

  float* fw = (float*)d_ws;
  float* q    = fw + OFF_Q;
  float* qpe  = fw + OFF_QPE;
  float* qca  = fw + OFF_QCA;
  float* tmp  = fw + OFF_TMP;
  float* pm   = fw + OFF_PM;
  float* ps   = fw + OFF_PS;
  float* po   = fw + OFF_PO;
  float* fpos = fw + OFF_FPOS;
  float* ctr  = fw + OFF_CTR;
  float* sig2 = fw + OFF_SIG;
  bf16* bw   = (bf16*)((char*)d_ws + F_TOTAL*sizeof(float));
  bf16* keys = bw + B_KEYS;
  bf16* kh   = bw + B_KH;
  bf16* vh   = bw + B_VH;
  bf16* kpe  = bw + B_KPE;

  k_transpose<<<dim3(175,4,6), dim3(32,8), 0, stream>>>(iff, keys, ln1_g);
  k_feat_pos<<<22, 256, 0, stream>>>(nifp, fpos, ln1_g);
  k_prep<<<200, 64, 0, stream>>>(niqp, l2i, view, ctr, d_out, ln1_g);
  k_pred0<<<200, 128, 0, stream>>>(iqf, q, pred_w1, pred_b1, pred_w2, pred_b2, sig2, ln1_g);

  for (int l = 0; l < 2; ++l){
    k_kpe_mfma<<<88, 256, 0, stream>>>(nifp, kpos_w1, l*256L, kpos_b1, l*128L,
                                       kpos_w2, l*16384L, kpos_b2, l*128L, kpe, ln1_g);
    k_saqkv<<<200, 384, 0, stream>>>(q, niqp, qpos_w1, l*256L, qpos_b1, l*128L,
                                     qpos_w2, l*16384L, qpos_b2, l*128L,
                                     sa_qkv_w, l*49152L, sa_qkv_b, l*384L, qpe, tmp, ln1_g);
    k_self_attn_f<<<200, 128, 0, stream>>>(tmp, view, sa_out_w, l*16384L, sa_out_b, l*128L,
                                           q, ln1_g, l*128L, ln1_b, l*128L,
                                           qpe, ca_qkv_w, l*49152L, ca_qkv_b, l*384L, qca, ln1_g);
    k_kv_proj_mfma<<<525, 256, 0, stream>>>(keys, kpe, ca_qkv_w, l*49152L, ca_qkv_b, l*384L,
                                            kh, vh, ln1_g);
    k_cross_part<<<dim3(NC,8,6), 256, 0, stream>>>(qca, kh, vh, fpos, ctr, sig2, view, pm, ps, po);
    k_tail<<<200, 256, 0, stream>>>(pm, ps, po, ca_out_w, l*16384L, ca_out_b, l*128L, q,
                                    ln2_g, l*128L, ln2_b, l*128L,
                                    ffn_w1, l*32768L, ffn_b1, l*256L,
                                    ffn_w2, l*32768L, ffn_b2, l*128L,
                                    ln3_g, l*128L, ln3_b, l*128L,
                                    pred_w1, pred_b1, pred_w2, pred_b2,
                                    niqp, d_out, (l==0 ? 45200L : 46400L), sig2,
                                    (l==1) ? 1 : 0, ln1_g);
  }
}

// Round 7
// 467.819 us; speedup vs baseline: 1.3572x; 1.2823x over previous
//
#include <hip/hip_runtime.h>
#include <hip/hip_bf16.h>
#include <cstdint>
#include <cstddef>

using bf16 = __hip_bfloat16;
#define DEV __device__ __forceinline__

typedef short s16x8 __attribute__((ext_vector_type(8)));
typedef float f32x4 __attribute__((ext_vector_type(4)));

DEV float b2f(bf16 x){ return __bfloat162float(x); }
DEV bf16  f2b(float x){ return __float2bfloat16(x); }
DEV float u2f(unsigned u){ union{unsigned u; float f;} c; c.u=u; return c.f; }
DEV unsigned f2u(float f){ union{float f; unsigned u;} c; c.f=f; return c.u; }
DEV unsigned short f2bu(float f){ unsigned u = f2u(f); u += 0x7FFFu + ((u>>16)&1u); return (unsigned short)(u>>16); }
DEV float sigm(float x){ return 1.f/(1.f+__expf(-x)); }
DEV int get_bf(const void* ln1g){ return ((*(const unsigned*)ln1g) & 0xFFFFu) == 0x3F80u; }

DEV float ld(const void* p, long i, int bf){
  return bf ? b2f(((const bf16*)p)[i]) : ((const float*)p)[i];
}
DEV void st(void* p, long i, float v, int bf){
  if (bf) ((bf16*)p)[i] = f2b(v); else ((float*)p)[i] = v;
}

constexpr float IMGX = 100.0f;
constexpr float IMGY = 56.0f;
constexpr float LOG_EPS = -15.942385f;
constexpr float BIN = 53.0f/1056.0f;
constexpr int NC = 35;
constexpr int CK = 160;

// ---- fp32 weight buffer offsets (floats) ----
constexpr int WO_SAQKVW = 0;        // 98304
constexpr int WO_SAQKVB = 98304;    // 768
constexpr int WO_SAOW   = 99072;    // 32768
constexpr int WO_SAOB   = 131840;   // 256
constexpr int WO_CAQKVW = 132096;   // 98304
constexpr int WO_CAQKVB = 230400;   // 768
constexpr int WO_CAOW   = 231168;   // 32768
constexpr int WO_CAOB   = 263936;   // 256
constexpr int WO_LN1G   = 264192;   // 256
constexpr int WO_LN1B   = 264448;
constexpr int WO_LN2G   = 264704;
constexpr int WO_LN2B   = 264960;
constexpr int WO_LN3G   = 265216;
constexpr int WO_LN3B   = 265472;
constexpr int WO_FW1    = 265728;   // 65536
constexpr int WO_FB1    = 331264;   // 512
constexpr int WO_FW2    = 331776;   // 65536
constexpr int WO_FB2    = 397312;   // 256
constexpr int WO_QW1    = 397568;   // 512
constexpr int WO_QB1    = 398080;   // 256
constexpr int WO_QW2    = 398336;   // 32768
constexpr int WO_QB2    = 431104;   // 256
constexpr int WO_KW1    = 431360;   // 512
constexpr int WO_KB1    = 431872;   // 256
constexpr int WO_KB2    = 432128;   // 256
constexpr int WO_PW1    = 432384;   // 16384
constexpr int WO_PB1    = 448768;   // 128
constexpr int WO_PW2    = 448896;   // 768
constexpr int WO_PB2    = 449664;   // 6
constexpr int W_TOTAL   = 449680;

// ---- workspace layout (floats) ----
constexpr size_t OFF_Q    = 0;        // 200*128
constexpr size_t OFF_QPE  = 25600;
constexpr size_t OFF_QCA  = 51200;
constexpr size_t OFF_TMP  = 76800;    // 200*384
constexpr size_t OFF_PM   = 153600;   // 200*35*8
constexpr size_t OFF_PS   = 209600;
constexpr size_t OFF_PO   = 265600;   // 200*35*8*16
constexpr size_t OFF_FPOS = 1161600;  // 5600*2
constexpr size_t OFF_CTR  = 1172800;
constexpr size_t OFF_SIG  = 1173200;
constexpr size_t OFF_WB   = 1173408;
constexpr size_t F_TOTAL  = OFF_WB + W_TOTAL;   // 1623088
// bf16 region:
constexpr size_t B_KEYS = 0;          // 33600*128
constexpr size_t B_KH   = 4300800;
constexpr size_t B_VH   = 8601600;
constexpr size_t B_KPE  = 12902400;   // 5600*128
constexpr size_t B_WKVT = 13619200;   // 2*256*128
constexpr size_t B_KW2T = 13684736;   // 2*128*128

DEV void unpack2(unsigned u, float* f){ f[0]=u2f(u<<16); f[1]=u2f(u&0xffff0000u); }

template<int W>
DEV void mergeW(float& m, float& s, float (&o)[16]){
  #pragma unroll
  for (int off=W/2; off>=1; off>>=1){
    float m2 = __shfl_xor(m, off);
    float s2 = __shfl_xor(s, off);
    float mn = fmaxf(m, m2);
    float ea = (m  > -3.0e38f) ? __expf(m  - mn) : 0.f;
    float eb = (m2 > -3.0e38f) ? __expf(m2 - mn) : 0.f;
    s = s*ea + s2*eb;
    #pragma unroll
    for (int d=0; d<16; ++d){
      float od = __shfl_xor(o[d], off);
      o[d] = o[d]*ea + od*eb;
    }
    m = mn;
  }
}

DEV float wsum64(float v){
  #pragma unroll
  for (int off=32; off; off>>=1) v += __shfl_xor(v, off);
  return v;
}

// ================= weight conversion =================
struct Seg { const void* src; int off; int n; };
struct CvtArgs { Seg s[29]; };

__global__ void k_cvt(CvtArgs a, float* dst, const void* ln1g){
  int bf = get_bf(ln1g);
  Seg sg = a.s[blockIdx.x];
  for (int i = blockIdx.y*blockDim.x + threadIdx.x; i < sg.n; i += gridDim.y*blockDim.x)
    dst[sg.off + i] = ld(sg.src, i, bf);
}

// ca_qkv_w K/V cols -> bf16 [l][n(256)][k(128)]
__global__ __launch_bounds__(128) void k_wkvT(const void* __restrict__ src, bf16* __restrict__ dst,
                                              const void* __restrict__ ln1g){
  int bf = get_bf(ln1g);
  int c = blockIdx.x, l = blockIdx.y, k = threadIdx.x;
  float v = ld(src, (long)l*49152 + (long)k*384 + 128 + c, bf);
  dst[((size_t)l*256 + c)*128 + k] = f2b(v);
}

// kpos_w2 -> bf16 [l][c(128)][k(128)]
__global__ __launch_bounds__(128) void k_kw2T(const void* __restrict__ src, bf16* __restrict__ dst,
                                              const void* __restrict__ ln1g){
  int bf = get_bf(ln1g);
  int c = blockIdx.x, l = blockIdx.y, k = threadIdx.x;
  float v = ld(src, (long)l*16384 + (long)k*128 + c, bf);
  dst[((size_t)l*128 + c)*128 + k] = f2b(v);
}

// ================= prep =================
__global__ void k_transpose(const void* __restrict__ iff, bf16* __restrict__ keys,
                            const void* __restrict__ ln1g){
  __shared__ float t[32][33];
  int bf = get_bf(ln1g);
  int k0 = blockIdx.x*32, c0 = blockIdx.y*32, v = blockIdx.z;
  int tx = threadIdx.x, ty = threadIdx.y;
  #pragma unroll
  for (int i=0;i<4;++i){
    int c = c0 + ty + i*8;
    t[ty+i*8][tx] = ld(iff, (long)(v*128 + c)*5600 + k0 + tx, bf);
  }
  __syncthreads();
  #pragma unroll
  for (int i=0;i<4;++i){
    int k = k0 + ty + i*8;
    keys[(size_t)(v*5600 + k)*128 + c0 + tx] = f2b(t[tx][ty+i*8]);
  }
}

__global__ void k_feat_pos(const void* __restrict__ nifp, float* __restrict__ fpos,
                           const void* __restrict__ ln1g){
  int bf = get_bf(ln1g);
  int k = blockIdx.x*blockDim.x + threadIdx.x;
  if (k >= 5600) return;
  fpos[2*k]   = sigm(ld(nifp,2*k,bf))*IMGX - 0.5f;
  fpos[2*k+1] = sigm(ld(nifp,2*k+1,bf))*IMGY - 0.5f;
}

__global__ __launch_bounds__(64) void k_prep(
    const void* __restrict__ niqp, const void* __restrict__ l2i,
    const int* __restrict__ view, float* __restrict__ ctr,
    void* __restrict__ out, const void* __restrict__ ln1g){
  __shared__ float M[16];
  __shared__ float cs[2];
  int bf = get_bf(ln1g);
  int n = blockIdx.x, t = threadIdx.x;
  if (t == 0){
    float p0 = ld(niqp,2*n,bf), p1 = ld(niqp,2*n+1,bf);
    float cx = sigm(p0)*IMGX, cy = sigm(p1)*IMGY;
    ctr[2*n] = cx; ctr[2*n+1] = cy;
    cs[0] = cx; cs[1] = cy;
    st(out, 25600 + 2*n,   p0, bf);
    st(out, 25600 + 2*n+1, p1, bf);
    int v = view[n];
    float a[4][8];
    for (int i=0;i<4;++i)
      for (int j=0;j<4;++j){ a[i][j] = ld(l2i, v*16+i*4+j, bf); a[i][4+j] = (i==j)?1.f:0.f; }
    for (int col=0; col<4; ++col){
      int p = col; float best = fabsf(a[col][col]);
      for (int r=col+1;r<4;++r){ float tt=fabsf(a[r][col]); if (tt>best){best=tt;p=r;} }
      if (p!=col) for (int j=0;j<8;++j){ float tt=a[col][j]; a[col][j]=a[p][j]; a[p][j]=tt; }
      float inv = 1.f/a[col][col];
      for (int j=0;j<8;++j) a[col][j]*=inv;
      for (int r=0;r<4;++r){
        if (r==col) continue;
        float f = a[r][col];
        for (int j=0;j<8;++j) a[r][j] -= f*a[col][j];
      }
    }
    for (int i=0;i<4;++i) for (int j=0;j<4;++j) M[i*4+j] = a[i][4+j];
  }
  __syncthreads();
  if (t < 32){
    int d = t;
    float px = cs[0]*8.f, py = cs[1]*8.f;
    float dep = 1.f + BIN * (float)d * (float)(d+1);
    float x = px*dep, y = py*dep;
    #pragma unroll
    for (int i=0;i<3;++i){
      float val = M[i*4]*x + M[i*4+1]*y + M[i*4+2]*dep + M[i*4+3];
      st(out, 26000 + n*96 + d*3 + i, val, bf);
    }
  }
}

// init q + pre-loop sigma (fp32 weights)
__global__ __launch_bounds__(128) void k_pred0(
    const void* __restrict__ iqf, float* __restrict__ q, const float* __restrict__ wb,
    float* __restrict__ is2p, const void* __restrict__ ln1g){
  __shared__ float xs[128];
  __shared__ float acc[6*128];
  __shared__ float bbv[8];
  int bf = get_bf(ln1g);
  int n = blockIdx.x, t = threadIdx.x;
  float xv = ld(iqf, (long)t*200 + n, bf);
  q[(size_t)n*128 + t] = xv;
  xs[t] = xv;
  __syncthreads();
  float a = wb[WO_PB1 + t];
  const float* W = wb + WO_PW1;
  for (int k = 0; k < 128; ++k) a = fmaf(xs[k], W[k*128 + t], a);
  float x = fmaxf(a, 0.f);
  #pragma unroll
  for (int c=0;c<6;++c) acc[c*128+t] = x * wb[WO_PW2 + t*6 + c];
  __syncthreads();
  for (int off=64; off; off>>=1){
    if (t < off){
      #pragma unroll
      for (int c=0;c<6;++c) acc[c*128+t] += acc[c*128+t+off];
    }
    __syncthreads();
  }
  if (t < 6) bbv[t] = acc[t*128] + wb[WO_PB2 + t];
  __syncthreads();
  if (t == 0){
    float dxv = sigm(bbv[2]) * IMGX;
    float dyv = sigm(bbv[3]) * IMGY;
    float rad = ceilf(sqrtf(dxv*dxv + dyv*dyv) * 0.5f);
    float sg = (rad*2.f + 1.f) * (1.f/6.f);
    is2p[n] = 1.f/(2.f*sg*sg);
  }
}

// ================= kpe via MFMA (B frags from pre-transposed bf16) =================
__global__ __launch_bounds__(256) void k_kpe_mfma(
    const void* __restrict__ nifp, const float* __restrict__ wb, int l,
    const bf16* __restrict__ kw2T, bf16* __restrict__ kpe, const void* __restrict__ ln1g){
  constexpr int XP = 136;
  __shared__ __align__(16) unsigned short xs[64*XP];
  __shared__ float2 pr[64];
  int bf = get_bf(ln1g);
  int r0 = blockIdx.x * 64;
  int tid = threadIdx.x;
  if (tid < 64){
    int k = r0 + tid; if (k > 5599) k = 5599;
    pr[tid] = make_float2(ld(nifp,2*k,bf), ld(nifp,2*k+1,bf));
  }
  __syncthreads();
  const float* w1 = wb + WO_KW1 + l*256;
  const float* b1 = wb + WO_KB1 + l*128;
  for (int idx = tid; idx < 64*64; idx += 256){
    int r = idx >> 6, c2 = (idx & 63)*2;
    float2 p = pr[r];
    #pragma unroll
    for (int u=0;u<2;++u){
      int c = c2+u;
      float a = fmaf(p.x, w1[c], fmaf(p.y, w1[128+c], b1[c]));
      xs[r*XP + c] = f2bu(fmaxf(a, 0.f));
    }
  }
  int wv = tid >> 6;
  int lane = tid & 63;
  int l16 = lane & 15, quad = lane >> 4;
  f32x4 acc[4][2];
  #pragma unroll
  for (int mt=0;mt<4;++mt)
    #pragma unroll
    for (int nt=0;nt<2;++nt) acc[mt][nt] = (f32x4){0.f,0.f,0.f,0.f};
  __syncthreads();
  #pragma unroll
  for (int kc = 0; kc < 4; ++kc){
    s16x8 bfr[2];
    #pragma unroll
    for (int nt = 0; nt < 2; ++nt){
      int col = wv*32 + nt*16 + l16;
      bfr[nt] = *(const s16x8*)&kw2T[((size_t)l*128 + col)*128 + kc*32 + quad*8];
    }
    s16x8 afr[4];
    #pragma unroll
    for (int mt = 0; mt < 4; ++mt)
      afr[mt] = *(const s16x8*)&xs[(mt*16 + l16)*XP + kc*32 + quad*8];
    #pragma unroll
    for (int mt = 0; mt < 4; ++mt)
      #pragma unroll
      for (int nt = 0; nt < 2; ++nt)
        acc[mt][nt] = __builtin_amdgcn_mfma_f32_16x16x32_bf16(afr[mt], bfr[nt], acc[mt][nt], 0, 0, 0);
  }
  float bv[2];
  #pragma unroll
  for (int nt=0;nt<2;++nt) bv[nt] = wb[WO_KB2 + l*128 + wv*32 + nt*16 + l16];
  #pragma unroll
  for (int mt = 0; mt < 4; ++mt)
    #pragma unroll
    for (int i = 0; i < 4; ++i){
      int gr = r0 + mt*16 + quad*4 + i;
      if (gr < 5600){
        #pragma unroll
        for (int nt = 0; nt < 2; ++nt)
          kpe[(size_t)gr*128 + wv*32 + nt*16 + l16] = f2b(acc[mt][nt][i] + bv[nt]);
      }
    }
}

// ================= fused qpe + sa_qkv projection =================
__global__ __launch_bounds__(384) void k_saqkv(
    const float* __restrict__ q, const void* __restrict__ niqp,
    const float* __restrict__ wb, int l,
    float* __restrict__ qpe_g, float* __restrict__ tmp, const void* __restrict__ ln1g){
  __shared__ float hs[128];
  __shared__ float xq[128];
  int bf = get_bf(ln1g);
  int n = blockIdx.x, t = threadIdx.x;
  if (t < 128){
    float p0 = ld(niqp,2*n,bf), p1 = ld(niqp,2*n+1,bf);
    float a = fmaf(p0, wb[WO_QW1 + l*256 + t], fmaf(p1, wb[WO_QW1 + l*256 + 128 + t], wb[WO_QB1 + l*128 + t]));
    hs[t] = fmaxf(a, 0.f);
  }
  __syncthreads();
  if (t < 128){
    const float* W = wb + WO_QW2 + l*16384;
    float a = wb[WO_QB2 + l*128 + t];
    for (int k = 0; k < 128; ++k) a = fmaf(hs[k], W[k*128 + t], a);
    qpe_g[(size_t)n*128 + t] = a;
    xq[t] = q[(size_t)n*128 + t] + a;
  }
  __syncthreads();
  const float* W = wb + WO_SAQKVW + l*49152;
  float acc = wb[WO_SAQKVB + l*384 + t];
  for (int k = 0; k < 128; ++k) acc = fmaf(xq[k], W[k*384 + t], acc);
  tmp[(size_t)n*384 + t] = acc;
}

// ================= self-attn + out-proj + LN1 + ca-q projection =================
__global__ __launch_bounds__(128) void k_self_attn_f(
    const float* __restrict__ qkv, const int* __restrict__ view,
    const float* __restrict__ wb, int l,
    float* __restrict__ q, const float* __restrict__ qpe_g, float* __restrict__ qca){
  __shared__ float att[128];
  __shared__ float red[128];
  __shared__ float xs2[128];
  int n = blockIdx.x, t = threadIdx.x;
  int h = t >> 4, j = t & 15;
  int vn = view[n];
  float qh[16];
  #pragma unroll
  for (int d=0; d<16; ++d) qh[d] = qkv[(size_t)n*384 + h*16 + d] * 0.25f;
  float m = -INFINITY, s = 0.f, o[16];
  #pragma unroll
  for (int d=0; d<16; ++d) o[d]=0.f;
  for (int k = j; k < 200; k += 16){
    float l2;
    if (view[k] != vn){ l2 = -INFINITY; }
    else {
      const float* kr = qkv + (size_t)k*384 + 128 + h*16;
      l2 = 0.f;
      #pragma unroll
      for (int d=0; d<16; ++d) l2 = fmaf(qh[d], kr[d], l2);
    }
    float mn = fmaxf(m, l2);
    float ea = (m > -3.0e38f) ? __expf(m - mn) : 0.f;
    float p  = (l2 > -3.0e38f) ? __expf(l2 - mn) : 0.f;
    s = s*ea + p;
    const float* vr = qkv + (size_t)k*384 + 256 + h*16;
    #pragma unroll
    for (int d=0; d<16; ++d) o[d] = o[d]*ea + p*vr[d];
    m = mn;
  }
  mergeW<16>(m, s, o);
  if (j == 0){
    float inv = (s > 0.f) ? 1.f/s : 0.f;
    #pragma unroll
    for (int d=0; d<16; ++d) att[h*16 + d] = o[d]*inv;
  }
  __syncthreads();
  const float* W = wb + WO_SAOW + l*16384;
  float acc = wb[WO_SAOB + l*128 + t];
  for (int k = 0; k < 128; ++k) acc = fmaf(att[k], W[k*128 + t], acc);
  float v = q[(size_t)n*128 + t] + acc;
  red[t] = v; __syncthreads();
  for (int off=64; off; off>>=1){ if (t<off) red[t]+=red[t+off]; __syncthreads(); }
  float mean = red[0]*(1.f/128.f);
  __syncthreads();
  float d = v - mean;
  red[t] = d*d; __syncthreads();
  for (int off=64; off; off>>=1){ if (t<off) red[t]+=red[t+off]; __syncthreads(); }
  float var = red[0]*(1.f/128.f);
  float r = rsqrtf(var + 1e-5f);
  float qn = d*r*wb[WO_LN1G + l*128 + t] + wb[WO_LN1B + l*128 + t];
  q[(size_t)n*128 + t] = qn;
  xs2[t] = qn + qpe_g[(size_t)n*128 + t];
  __syncthreads();
  const float* Wc = wb + WO_CAQKVW + l*49152;
  float a2 = wb[WO_CAQKVB + l*384 + t];
  for (int k = 0; k < 128; ++k) a2 = fmaf(xs2[k], Wc[k*384 + t], a2);
  qca[(size_t)n*128 + t] = a2;
}

// ================= K/V projection — MFMA =================
__global__ __launch_bounds__(256) void k_kv_proj_mfma(
    const bf16* __restrict__ keys, const bf16* __restrict__ kpe,
    const bf16* __restrict__ wkvT, const float* __restrict__ wb, int l,
    bf16* __restrict__ kh, bf16* __restrict__ vh){
  constexpr int XP = 136;
  __shared__ __align__(16) unsigned short xs[64*XP];
  int r0 = blockIdx.x * 64;
  int tid = threadIdx.x;
  for (int idx = tid; idx < 64*64; idx += 256){
    int r = idx >> 6, c2 = (idx & 63)*2;
    int gr = r0 + r;
    int v = gr / 5600; int k = gr - v*5600;
    float a0 = b2f(keys[(size_t)gr*128 + c2])   + b2f(kpe[(size_t)k*128 + c2]);
    float a1 = b2f(keys[(size_t)gr*128 + c2+1]) + b2f(kpe[(size_t)k*128 + c2+1]);
    xs[r*XP + c2]   = f2bu(a0);
    xs[r*XP + c2+1] = f2bu(a1);
  }
  int wv = tid >> 6;
  int lane = tid & 63;
  int l16 = lane & 15, quad = lane >> 4;
  f32x4 acc[4][4];
  #pragma unroll
  for (int mt=0;mt<4;++mt)
    #pragma unroll
    for (int nt=0;nt<4;++nt) acc[mt][nt] = (f32x4){0.f,0.f,0.f,0.f};
  __syncthreads();
  #pragma unroll
  for (int kc = 0; kc < 4; ++kc){
    s16x8 bfr[4];
    #pragma unroll
    for (int nt = 0; nt < 4; ++nt){
      int col = wv*64 + nt*16 + l16;
      bfr[nt] = *(const s16x8*)&wkvT[((size_t)l*256 + col)*128 + kc*32 + quad*8];
    }
    s16x8 afr[4];
    #pragma unroll
    for (int mt = 0; mt < 4; ++mt)
      afr[mt] = *(const s16x8*)&xs[(mt*16 + l16)*XP + kc*32 + quad*8];
    #pragma unroll
    for (int mt = 0; mt < 4; ++mt)
      #pragma unroll
      for (int nt = 0; nt < 4; ++nt)
        acc[mt][nt] = __builtin_amdgcn_mfma_f32_16x16x32_bf16(afr[mt], bfr[nt], acc[mt][nt], 0, 0, 0);
  }
  float bv[4];
  bf16* op[4];
  long ntOff[4];
  #pragma unroll
  for (int nt = 0; nt < 4; ++nt){
    int c = wv*64 + nt*16 + l16;
    bv[nt] = wb[WO_CAQKVB + l*384 + 128 + c];
    int sel = c >> 7, ch = c & 127;
    int h = ch >> 4, d = ch & 15;
    op[nt] = sel ? vh : kh;
    ntOff[nt] = (long)h*89600 + d;
  }
  #pragma unroll
  for (int mt = 0; mt < 4; ++mt)
    #pragma unroll
    for (int i = 0; i < 4; ++i){
      int gr = r0 + mt*16 + quad*4 + i;
      int v = gr / 5600; int k = gr - v*5600;
      long rowOff = (long)v*716800 + (long)k*16;
      #pragma unroll
      for (int nt = 0; nt < 4; ++nt)
        op[nt][rowOff + ntOff[nt]] = f2b(acc[mt][nt][i] + bv[nt]);
    }
}

// ================= cross-attention partial =================
__global__ __launch_bounds__(256) void k_cross_part(
    const float* __restrict__ qca, const bf16* __restrict__ kh, const bf16* __restrict__ vh,
    const float* __restrict__ fpos, const float* __restrict__ ctr,
    const float* __restrict__ is2p, const int* __restrict__ view,
    float* __restrict__ pm, float* __restrict__ ps, float* __restrict__ po){
  __shared__ __align__(16) unsigned short KV[CK][36];
  __shared__ float2 fp[CK];
  __shared__ int qlist[200];
  __shared__ int qcnt;
  int ch = blockIdx.x, h = blockIdx.y, v = blockIdx.z;
  int t = threadIdx.x;
  int k0 = ch*CK;
  if (t == 0) qcnt = 0;
  const uint2* ks = (const uint2*)(kh + ((size_t)(v*8 + h)*5600 + k0)*16);
  const uint2* vs = (const uint2*)(vh + ((size_t)(v*8 + h)*5600 + k0)*16);
  for (int i = t; i < CK*4; i += 256){
    int key = i >> 2, part = i & 3;
    *(uint2*)&KV[key][part*4]      = ks[i];
    *(uint2*)&KV[key][16 + part*4] = vs[i];
  }
  if (t < CK) fp[t] = ((const float2*)fpos)[k0 + t];
  __syncthreads();
  if (t < 200 && view[t] == v){ int i = atomicAdd(&qcnt, 1); qlist[i] = t; }
  __syncthreads();
  int nq = qcnt;
  int g = t >> 5, j = t & 31;
  for (int p = g; p < nq; p += 8){
    int n = qlist[p];
    float cx = ctr[2*n], cy = ctr[2*n+1];
    float is2 = is2p[n];
    float qh[16];
    const float* qrow = qca + (size_t)n*128 + h*16;
    #pragma unroll
    for (int d=0; d<16; ++d) qh[d] = qrow[d] * 0.25f;
    float m = -INFINITY, s = 0.f, o[16];
    #pragma unroll
    for (int d=0; d<16; ++d) o[d]=0.f;
    #pragma unroll
    for (int i = 0; i < CK/32; ++i){
      int key = i*32 + j;
      float2 pxy = fp[key];
      float dx = cx - pxy.x, dy = cy - pxy.y;
      float gg = -(dx*dx + dy*dy) * is2;
      const uint2* kp = (const uint2*)&KV[key][0];
      const uint2* vp = (const uint2*)&KV[key][16];
      float kf[16], vf[16];
      #pragma unroll
      for (int u=0; u<4; ++u){
        uint2 a = kp[u]; unpack2(a.x, kf+u*4); unpack2(a.y, kf+u*4+2);
        uint2 b = vp[u]; unpack2(b.x, vf+u*4); unpack2(b.y, vf+u*4+2);
      }
      float l = gg;
      #pragma unroll
      for (int d=0; d<16; ++d) l = fmaf(qh[d], kf[d], l);
      l = (gg < LOG_EPS) ? -INFINITY : l;
      float mn = fmaxf(m, l);
      float ea = (m > -3.0e38f) ? __expf(m - mn) : 0.f;
      float pr = (l > -3.0e38f) ? __expf(l - mn) : 0.f;
      s = s*ea + pr;
      #pragma unroll
      for (int d=0; d<16; ++d) o[d] = o[d]*ea + pr*vf[d];
      m = mn;
    }
    mergeW<32>(m, s, o);
    if (j == 0){
      int idx = (n*NC + ch)*8 + h;
      pm[idx] = m; ps[idx] = s;
      float4* o4 = (float4*)(po + (size_t)idx*16);
      o4[0] = make_float4(o[0],o[1],o[2],o[3]);
      o4[1] = make_float4(o[4],o[5],o[6],o[7]);
      o4[2] = make_float4(o[8],o[9],o[10],o[11]);
      o4[3] = make_float4(o[12],o[13],o[14],o[15]);
    }
  }
}

// ================= tail (split-K parallel, shuffle LNs) =================
__global__ __launch_bounds__(256) void k_tail(
    const float* __restrict__ pm, const float* __restrict__ ps, const float* __restrict__ po,
    const float* __restrict__ wb, int l, float* __restrict__ q,
    const void* __restrict__ niqp, void* __restrict__ out, long outOff,
    float* __restrict__ is2p, int last, const void* __restrict__ ln1g){
  __shared__ float att[128];
  __shared__ float sm[2][128], ss[2][128], so[2][128];
  __shared__ float part[256];
  __shared__ float redw[4];
  __shared__ float xs[128];
  __shared__ float hs[256];
  __shared__ float ac6[6*128];
  __shared__ float bbv[8];
  int bf = get_bf(ln1g);
  int n = blockIdx.x, t = threadIdx.x;
  int tc = t & 127, half = t >> 7;
  // merge over split c ranges
  {
    int h = tc >> 4, d = tc & 15;
    int c0 = half ? 18 : 0, c1 = half ? NC : 18;
    float m = -INFINITY, s = 0.f, o = 0.f;
    for (int c = c0; c < c1; ++c){
      int idx = (n*NC + c)*8 + h;
      float mc = pm[idx], sc = ps[idx], oc = po[(size_t)idx*16 + d];
      float mn = fmaxf(m, mc);
      float ea = (m  > -3.0e38f) ? __expf(m  - mn) : 0.f;
      float eb = (mc > -3.0e38f) ? __expf(mc - mn) : 0.f;
      s = s*ea + sc*eb;
      o = o*ea + oc*eb;
      m = mn;
    }
    sm[half][tc]=m; ss[half][tc]=s; so[half][tc]=o;
  }
  __syncthreads();
  if (t < 128){
    float m1=sm[0][t], m2=sm[1][t];
    float mn=fmaxf(m1,m2);
    float e1=(m1>-3.0e38f)?__expf(m1-mn):0.f, e2=(m2>-3.0e38f)?__expf(m2-mn):0.f;
    float s = ss[0][t]*e1 + ss[1][t]*e2;
    float o = so[0][t]*e1 + so[1][t]*e2;
    att[t] = (s>0.f)? o/s : 0.f;
  }
  __syncthreads();
  // out-proj split-K
  {
    const float* W = wb + WO_CAOW + l*16384;
    float a = 0.f;
    for (int k = half*64; k < half*64+64; ++k) a = fmaf(att[k], W[k*128 + tc], a);
    part[t] = a;
  }
  __syncthreads();
  float v = (t<128) ? q[(size_t)n*128 + t] + part[t] + part[128+t] + wb[WO_CAOB + l*128 + t] : 0.f;
  // LN2
  float sv = wsum64(v);
  if ((t&63)==0) redw[t>>6] = sv;
  __syncthreads();
  float mean = (redw[0]+redw[1]+redw[2]+redw[3]) * (1.f/128.f);
  __syncthreads();
  float d = (t<128)? v-mean : 0.f;
  sv = wsum64(d*d);
  if ((t&63)==0) redw[t>>6] = sv;
  __syncthreads();
  float var = (redw[0]+redw[1]+redw[2]+redw[3]) * (1.f/128.f);
  float r = rsqrtf(var + 1e-5f);
  if (t<128) xs[t] = d*r*wb[WO_LN2G + l*128 + t] + wb[WO_LN2B + l*128 + t];
  __syncthreads();
  // FFN1: all 256 threads
  {
    const float* W = wb + WO_FW1 + l*32768;
    float a = wb[WO_FB1 + l*256 + t];
    for (int k=0;k<128;++k) a = fmaf(xs[k], W[k*256 + t], a);
    hs[t] = fmaxf(a, 0.f);
  }
  __syncthreads();
  // FFN2 split-K
  {
    const float* W = wb + WO_FW2 + l*32768;
    float a = 0.f;
    for (int k=half*128;k<half*128+128;++k) a = fmaf(hs[k], W[k*128 + tc], a);
    part[t] = a;
  }
  __syncthreads();
  v = (t<128) ? xs[t] + part[t] + part[128+t] + wb[WO_FB2 + l*128 + t] : 0.f;
  // LN3
  sv = wsum64(v);
  if ((t&63)==0) redw[t>>6] = sv;
  __syncthreads();
  mean = (redw[0]+redw[1]+redw[2]+redw[3]) * (1.f/128.f);
  __syncthreads();
  d = (t<128)? v-mean : 0.f;
  sv = wsum64(d*d);
  if ((t&63)==0) redw[t>>6] = sv;
  __syncthreads();
  var = (redw[0]+redw[1]+redw[2]+redw[3]) * (1.f/128.f);
  r = rsqrtf(var + 1e-5f);
  if (t<128){
    float q3 = d*r*wb[WO_LN3G + l*128 + t] + wb[WO_LN3B + l*128 + t];
    q[(size_t)n*128 + t] = q3;
    xs[t] = q3;
    if (last) st(out, (long)t*200 + n, q3, bf);
  }
  __syncthreads();
  // pred hidden split-K
  {
    const float* W = wb + WO_PW1;
    float a = 0.f;
    for (int k=half*64;k<half*64+64;++k) a = fmaf(xs[k], W[k*128 + tc], a);
    part[t] = a;
  }
  __syncthreads();
  if (t<128){
    float x = fmaxf(part[t] + part[128+t] + wb[WO_PB1 + t], 0.f);
    #pragma unroll
    for (int c=0;c<6;++c) ac6[c*128+t] = x * wb[WO_PW2 + t*6 + c];
  }
  __syncthreads();
  for (int off=64; off; off>>=1){
    if (t < off){
      #pragma unroll
      for (int c=0;c<6;++c) ac6[c*128+t] += ac6[c*128+t+off];
    }
    __syncthreads();
  }
  if (t < 6){
    float raw = ac6[t*128] + wb[WO_PB2 + t];
    if (t < 2) raw += ld(niqp, 2*n + t, bf);
    float svv = sigm(raw);
    st(out, outOff + n*6 + t, svv, bf);
    bbv[t] = svv;
  }
  __syncthreads();
  if (t == 0){
    float dxv = sigm(bbv[2]) * IMGX;
    float dyv = sigm(bbv[3]) * IMGY;
    float rad = ceilf(sqrtf(dxv*dxv + dyv*dyv) * 0.5f);
    float sg = (rad*2.f + 1.f) * (1.f/6.f);
    is2p[n] = 1.f/(2.f*sg*sg);
  }
}

// ================= launch =================
extern "C" void kernel_launch(void* const* d_in, const int* in_sizes, int n_in,
                              void* d_out, int out_size, void* d_ws, size_t ws_size,
                              hipStream_t stream){
  const void* iqf   = d_in[0];
  const void* niqp  = d_in[1];
  const void* iff   = d_in[2];
  const void* nifp  = d_in[3];
  const void* l2i   = d_in[4];
  const int*  view  = (const int*)d_in[5];
  const void* ln1_g = d_in[14];

  float* fw = (float*)d_ws;
  float* q    = fw + OFF_Q;
  float* qpe  = fw + OFF_QPE;
  float* qca  = fw + OFF_QCA;
  float* tmp  = fw + OFF_TMP;
  float* pm   = fw + OFF_PM;
  float* ps   = fw + OFF_PS;
  float* po   = fw + OFF_PO;
  float* fpos = fw + OFF_FPOS;
  float* ctr  = fw + OFF_CTR;
  float* sig2 = fw + OFF_SIG;
  float* wb   = fw + OFF_WB;
  bf16* bw   = (bf16*)((char*)d_ws + F_TOTAL*sizeof(float));
  bf16* keys = bw + B_KEYS;
  bf16* kh   = bw + B_KH;
  bf16* vh   = bw + B_VH;
  bf16* kpe  = bw + B_KPE;
  bf16* wkvT = bw + B_WKVT;
  bf16* kw2T = bw + B_KW2T;

  CvtArgs ca;
  ca.s[0]  = {d_in[6],  WO_SAQKVW, 98304};
  ca.s[1]  = {d_in[7],  WO_SAQKVB, 768};
  ca.s[2]  = {d_in[8],  WO_SAOW,   32768};
  ca.s[3]  = {d_in[9],  WO_SAOB,   256};
  ca.s[4]  = {d_in[10], WO_CAQKVW, 98304};
  ca.s[5]  = {d_in[11], WO_CAQKVB, 768};
  ca.s[6]  = {d_in[12], WO_CAOW,   32768};
  ca.s[7]  = {d_in[13], WO_CAOB,   256};
  ca.s[8]  = {d_in[14], WO_LN1G,   256};
  ca.s[9]  = {d_in[15], WO_LN1B,   256};
  ca.s[10] = {d_in[16], WO_LN2G,   256};
  ca.s[11] = {d_in[17], WO_LN2B,   256};
  ca.s[12] = {d_in[18], WO_LN3G,   256};
  ca.s[13] = {d_in[19], WO_LN3B,   256};
  ca.s[14] = {d_in[20], WO_FW1,    65536};
  ca.s[15] = {d_in[21], WO_FB1,    512};
  ca.s[16] = {d_in[22], WO_FW2,    65536};
  ca.s[17] = {d_in[23], WO_FB2,    256};
  ca.s[18] = {d_in[24], WO_QW1,    512};
  ca.s[19] = {d_in[25], WO_QB1,    256};
  ca.s[20] = {d_in[26], WO_QW2,    32768};
  ca.s[21] = {d_in[27], WO_QB2,    256};
  ca.s[22] = {d_in[28], WO_KW1,    512};
  ca.s[23] = {d_in[29], WO_KB1,    256};
  ca.s[24] = {d_in[31], WO_KB2,    256};
  ca.s[25] = {d_in[32], WO_PW1,    16384};
  ca.s[26] = {d_in[33], WO_PB1,    128};
  ca.s[27] = {d_in[34], WO_PW2,    768};
  ca.s[28] = {d_in[35], WO_PB2,    6};

  k_cvt<<<dim3(29,8), 256, 0, stream>>>(ca, wb, ln1_g);
  k_wkvT<<<dim3(256,2), 128, 0, stream>>>(d_in[10], wkvT, ln1_g);
  k_kw2T<<<dim3(128,2), 128, 0, stream>>>(d_in[30], kw2T, ln1_g);
  k_transpose<<<dim3(175,4,6), dim3(32,8), 0, stream>>>(iff, keys, ln1_g);
  k_feat_pos<<<22, 256, 0, stream>>>(nifp, fpos, ln1_g);
  k_prep<<<200, 64, 0, stream>>>(niqp, l2i, view, ctr, d_out, ln1_g);
  k_pred0<<<200, 128, 0, stream>>>(iqf, q, wb, sig2, ln1_g);

  for (int l = 0; l < 2; ++l){
    k_kpe_mfma<<<88, 256, 0, stream>>>(nifp, wb, l, kw2T, kpe, ln1_g);
    k_saqkv<<<200, 384, 0, stream>>>(q, niqp, wb, l, qpe, tmp, ln1_g);
    k_self_attn_f<<<200, 128, 0, stream>>>(tmp, view, wb, l, q, qpe, qca);
    k_kv_proj_mfma<<<525, 256, 0, stream>>>(keys, kpe, wkvT, wb, l, kh, vh);
    k_cross_part<<<dim3(NC,8,6), 256, 0, stream>>>(qca, kh, vh, fpos, ctr, sig2, view, pm, ps, po);
    k_tail<<<200, 256, 0, stream>>>(pm, ps, po, wb, l, q, niqp, d_out,
                                    (l==0 ? 45200L : 46400L), sig2, (l==1) ? 1 : 0, ln1_g);
  }
}